// Round 1
// baseline (3360.154 us; speedup 1.0000x reference)
//
#include <hip/hip_runtime.h>
#include <math.h>

#define H 2048
#define DIN 784

// ---------- SPU math ----------
__device__ __forceinline__ float spu_f(float x){
    if (x >= 0.0f) return x*x - 0.5f;
    float s = 1.0f / (1.0f + __expf(x));   // sigmoid(-x)
    return s - 1.0f;
}
__device__ __forceinline__ float dspu_f(float x){
    if (x >= 0.0f) return 2.0f*x;
    float s = 1.0f / (1.0f + __expf(x));
    return -s * (1.0f - s);
}

// ---------- block reduce (blockDim.x == 256) ----------
__device__ __forceinline__ float block_reduce_256(float v, float* red){
    #pragma unroll
    for (int off = 32; off > 0; off >>= 1) v += __shfl_down(v, off, 64);
    int lane = threadIdx.x & 63, w = threadIdx.x >> 6;
    if (lane == 0) red[w] = v;
    __syncthreads();
    float t = 0.f;
    if (threadIdx.x == 0) t = red[0] + red[1] + red[2] + red[3];
    return t;   // valid on thread 0 only
}

// out[row] = sum_j max(M,0)*pos_b + min(M,0)*neg_b + c[row]
__global__ __launch_bounds__(256) void input_reduce(
    const float* __restrict__ M, const float* __restrict__ c,
    const float* __restrict__ pos_b, const float* __restrict__ neg_b,
    float* __restrict__ out, int ncols)
{
    __shared__ float red[4];
    int row = blockIdx.x;
    const float* Mr = M + (size_t)row * ncols;
    float acc = 0.f;
    for (int j = threadIdx.x; j < ncols; j += 256){
        float v = Mr[j];
        acc += fmaxf(v, 0.f) * pos_b[j] + fminf(v, 0.f) * neg_b[j];
    }
    float t = block_reduce_256(acc, red);
    if (threadIdx.x == 0) out[row] = t + c[row];
}

// Mout[i][j] = max(S,0)*w_pos[j] + min(S,0)*w_neg[j];
// c_out[i] = c_in[i] + sum_j max(S,0)*b_pos[j] + min(S,0)*b_neg[j]
__global__ __launch_bounds__(256) void dapply(
    const float* __restrict__ S, const float* __restrict__ c_in,
    const float* __restrict__ w_pos, const float* __restrict__ w_neg,
    const float* __restrict__ b_pos, const float* __restrict__ b_neg,
    float* __restrict__ Mout, float* __restrict__ c_out, int ncols)
{
    __shared__ float red[4];
    int row = blockIdx.x;
    const float* Sr = S + (size_t)row * ncols;
    float* Mr = Mout + (size_t)row * ncols;
    float acc = 0.f;
    for (int j = threadIdx.x; j < ncols; j += 256){
        float v = Sr[j];
        float p = fmaxf(v, 0.f), n = fminf(v, 0.f);
        Mr[j] = p * w_pos[j] + n * w_neg[j];
        acc += p * b_pos[j] + n * b_neg[j];
    }
    float t = block_reduce_256(acc, red);
    if (threadIdx.x == 0) c_out[row] = c_in[row] + t;
}

// elementwise slope clip + intercepts
__global__ void spu_bounds(
    const float* __restrict__ lf, const float* __restrict__ uf,
    const float* __restrict__ pl, const float* __restrict__ pu,
    float* __restrict__ wl, float* __restrict__ wu,
    float* __restrict__ bl, float* __restrict__ bu, int n)
{
    int i = blockIdx.x * blockDim.x + threadIdx.x;
    if (i >= n) return;
    float l = lf[i], u = uf[i];
    float k1 = dspu_f(l), k2 = dspu_f(u);
    float klo = fminf(k1, k2), khi = fmaxf(k1, k2);
    float cwl = fminf(fmaxf(pl[i], klo), khi);
    float cwu = fminf(fmaxf(pu[i], klo), khi);
    float pts[4];
    pts[0] = l; pts[1] = u; pts[2] = 0.5f*(l+u); pts[3] = fminf(fmaxf(0.f, l), u);
    float bmin = INFINITY, bmax = -INFINITY;
    #pragma unroll
    for (int t = 0; t < 4; t++){
        float sp = spu_f(pts[t]);
        bmin = fminf(bmin, sp - cwl * pts[t]);
        bmax = fmaxf(bmax, sp - cwu * pts[t]);
    }
    wl[i] = cwl; wu[i] = cwu; bl[i] = bmin; bu[i] = bmax;
}

// F[r][j] = W4[k_r][j] - W4[tl][j];  c9[r] = b4[k_r] - b4[tl]; k_r = r + (r>=tl)
__global__ void final_init(const float* __restrict__ W4, const float* __restrict__ b4,
                           const int* __restrict__ tl_p,
                           float* __restrict__ F, float* __restrict__ c9)
{
    int tl = *tl_p;
    int idx = blockIdx.x * blockDim.x + threadIdx.x;
    if (idx >= 9 * H) return;
    int r = idx / H, j = idx % H;
    int k = r + (r >= tl ? 1 : 0);
    F[idx] = W4[(size_t)k * H + j] - W4[(size_t)tl * H + j];
    if (j == 0) c9[r] = b4[k] - b4[tl];
}

// C[MxN] = A[MxK] @ B[KxN];  c_out[i] = c_in[i] + A_row . bias  (only bn==0 blocks)
#define BM 64
#define BN 64
#define BK 16
#define LDA (BM + 4)
#define LDB (BN + 4)
__global__ __launch_bounds__(256) void gemm_bias(
    const float* __restrict__ A, const float* __restrict__ B,
    const float* __restrict__ bias, const float* __restrict__ c_in,
    float* __restrict__ C, float* __restrict__ c_out,
    int M, int N, int K)
{
    __shared__ float Ast[BK][LDA];   // transposed A tile: Ast[kk][r]
    __shared__ float Bs[BK][LDB];
    __shared__ float bs[BK];
    int tid = threadIdx.x;
    int tx = tid & 15;       // col group 0..15
    int ty = tid >> 4;       // row group 0..15
    int bm = blockIdx.y, bn = blockIdx.x;
    int row0 = bm * BM, col0 = bn * BN;
    float acc[4][4] = {};
    float cacc[4] = {0.f, 0.f, 0.f, 0.f};

    for (int k0 = 0; k0 < K; k0 += BK){
        // A tile: 64 rows x 16 k, thread t loads (r = t/16 + 16p, kk = t%16)
        #pragma unroll
        for (int p = 0; p < 4; p++){
            int r  = (tid >> 4) + p * 16;
            int kk = tid & 15;
            int gr = row0 + r, gk = k0 + kk;
            Ast[kk][r] = (gr < M && gk < K) ? A[(size_t)gr * K + gk] : 0.f;
        }
        // B tile: 16 k x 64 cols, thread t loads (kk = t/64 + 4p, cc = t%64)
        #pragma unroll
        for (int p = 0; p < 4; p++){
            int kk = (tid >> 6) + p * 4;
            int cc = tid & 63;
            int gk = k0 + kk, gc = col0 + cc;
            Bs[kk][cc] = (gk < K && gc < N) ? B[(size_t)gk * N + gc] : 0.f;
        }
        if (tid < BK){
            int gk = k0 + tid;
            bs[tid] = (gk < K) ? bias[gk] : 0.f;
        }
        __syncthreads();
        #pragma unroll
        for (int kk = 0; kk < BK; kk++){
            float4 a4 = *(const float4*)&Ast[kk][ty * 4];
            float4 b4 = *(const float4*)&Bs[kk][tx * 4];
            float a[4] = {a4.x, a4.y, a4.z, a4.w};
            float b[4] = {b4.x, b4.y, b4.z, b4.w};
            #pragma unroll
            for (int i = 0; i < 4; i++)
                #pragma unroll
                for (int j = 0; j < 4; j++)
                    acc[i][j] += a[i] * b[j];
            if (tx == 0){
                float bb = bs[kk];
                #pragma unroll
                for (int i = 0; i < 4; i++) cacc[i] += a[i] * bb;
            }
        }
        __syncthreads();
    }
    #pragma unroll
    for (int i = 0; i < 4; i++){
        int gr = row0 + ty * 4 + i;
        if (gr >= M) continue;
        #pragma unroll
        for (int j = 0; j < 4; j++){
            int gc = col0 + tx * 4 + j;
            if (gc < N) C[(size_t)gr * N + gc] = acc[i][j];
        }
        if (tx == 0 && bn == 0) c_out[gr] = c_in[gr] + cacc[i];
    }
}

extern "C" void kernel_launch(void* const* d_in, const int* in_sizes, int n_in,
                              void* d_out, int out_size, void* d_ws, size_t ws_size,
                              hipStream_t stream)
{
    const float* W1  = (const float*)d_in[0];
    const float* b1  = (const float*)d_in[1];
    const float* W2  = (const float*)d_in[2];
    const float* b2  = (const float*)d_in[3];
    const float* W3  = (const float*)d_in[4];
    const float* b3  = (const float*)d_in[5];
    const float* W4  = (const float*)d_in[6];
    const float* b4  = (const float*)d_in[7];
    const float* l_in = (const float*)d_in[8];
    const float* u_in = (const float*)d_in[9];
    const float* p_l1 = (const float*)d_in[10];
    const float* p_u1 = (const float*)d_in[11];
    const float* p_l2 = (const float*)d_in[12];
    const float* p_u2 = (const float*)d_in[13];
    const float* p_l3 = (const float*)d_in[14];
    const float* p_u3 = (const float*)d_in[15];
    const int*   tl   = (const int*)d_in[16];
    float* out = (float*)d_out;

    // workspace layout
    size_t off = 0;
    auto alloc = [&](size_t nfloats) -> float* {
        float* p = (float*)((char*)d_ws + off);
        off += nfloats * sizeof(float);
        return p;
    };
    float* A_l = alloc((size_t)H * H);
    float* A_u = alloc((size_t)H * H);
    float* B_l = alloc((size_t)H * H);
    float* B_u = alloc((size_t)H * H);
    float* lf  = alloc(H);
    float* uf  = alloc(H);
    float* wl1 = alloc(H); float* wu1 = alloc(H); float* bl1 = alloc(H); float* bu1 = alloc(H);
    float* wl2 = alloc(H); float* wu2 = alloc(H); float* bl2 = alloc(H); float* bu2 = alloc(H);
    float* wl3 = alloc(H); float* wu3 = alloc(H); float* bl3 = alloc(H); float* bu3 = alloc(H);
    float* cl_a = alloc(H); float* cl_b = alloc(H);
    float* cu_a = alloc(H); float* cu_b = alloc(H);
    float* F0  = alloc(9 * H);
    float* F1  = alloc(9 * H);
    float* c9a = alloc(16);
    float* c9b = alloc(16);

    dim3 blk(256);

    // ---- stage 1: layer-1 pre-activation bounds (direct from W1,b1) ----
    input_reduce<<<H, blk, 0, stream>>>(W1, b1, l_in, u_in, lf, DIN);
    input_reduce<<<H, blk, 0, stream>>>(W1, b1, u_in, l_in, uf, DIN);
    spu_bounds<<<(H + 255)/256, blk, 0, stream>>>(lf, uf, p_l1, p_u1, wl1, wu1, bl1, bu1, H);

    dim3 gN(( H  + BN - 1)/BN, (H + BM - 1)/BM);   // 2048x2048 out
    dim3 gD((DIN + BN - 1)/BN, (H + BM - 1)/BM);   // 2048x784 out
    dim3 gN9((H  + BN - 1)/BN, 1);                 // 9x2048 out
    dim3 gD9((DIN + BN - 1)/BN, 1);                // 9x784 out

    // ---- stage 2 (B1): start (W2,b2) -> D1 -> @W1 -> input ----
    dapply<<<H, blk, 0, stream>>>(W2, b2, wl1, wu1, bl1, bu1, A_l, cl_a, H);
    dapply<<<H, blk, 0, stream>>>(W2, b2, wu1, wl1, bu1, bl1, A_u, cu_a, H);
    gemm_bias<<<gD, blk, 0, stream>>>(A_l, W1, b1, cl_a, B_l, cl_b, H, DIN, H);
    gemm_bias<<<gD, blk, 0, stream>>>(A_u, W1, b1, cu_a, B_u, cu_b, H, DIN, H);
    input_reduce<<<H, blk, 0, stream>>>(B_l, cl_b, l_in, u_in, lf, DIN);
    input_reduce<<<H, blk, 0, stream>>>(B_u, cu_b, u_in, l_in, uf, DIN);
    spu_bounds<<<(H + 255)/256, blk, 0, stream>>>(lf, uf, p_l2, p_u2, wl2, wu2, bl2, bu2, H);

    // ---- stage 3 (B2): start (W3,b3) -> D2 -> @W2 -> D1 -> @W1 -> input ----
    dapply<<<H, blk, 0, stream>>>(W3, b3, wl2, wu2, bl2, bu2, A_l, cl_a, H);
    dapply<<<H, blk, 0, stream>>>(W3, b3, wu2, wl2, bu2, bl2, A_u, cu_a, H);
    gemm_bias<<<gN, blk, 0, stream>>>(A_l, W2, b2, cl_a, B_l, cl_b, H, H, H);
    gemm_bias<<<gN, blk, 0, stream>>>(A_u, W2, b2, cu_a, B_u, cu_b, H, H, H);
    dapply<<<H, blk, 0, stream>>>(B_l, cl_b, wl1, wu1, bl1, bu1, A_l, cl_a, H);
    dapply<<<H, blk, 0, stream>>>(B_u, cu_b, wu1, wl1, bu1, bl1, A_u, cu_a, H);
    gemm_bias<<<gD, blk, 0, stream>>>(A_l, W1, b1, cl_a, B_l, cl_b, H, DIN, H);
    gemm_bias<<<gD, blk, 0, stream>>>(A_u, W1, b1, cu_a, B_u, cu_b, H, DIN, H);
    input_reduce<<<H, blk, 0, stream>>>(B_l, cl_b, l_in, u_in, lf, DIN);
    input_reduce<<<H, blk, 0, stream>>>(B_u, cu_b, u_in, l_in, uf, DIN);
    spu_bounds<<<(H + 255)/256, blk, 0, stream>>>(lf, uf, p_l3, p_u3, wl3, wu3, bl3, bu3, H);

    // ---- final chain (upper bound only), 9 rows ----
    final_init<<<(9*H + 255)/256, blk, 0, stream>>>(W4, b4, tl, F0, c9a);
    dapply<<<9, blk, 0, stream>>>(F0, c9a, wu3, wl3, bu3, bl3, F1, c9b, H);
    gemm_bias<<<gN9, blk, 0, stream>>>(F1, W3, b3, c9b, F0, c9a, 9, H, H);
    dapply<<<9, blk, 0, stream>>>(F0, c9a, wu2, wl2, bu2, bl2, F1, c9b, H);
    gemm_bias<<<gN9, blk, 0, stream>>>(F1, W2, b2, c9b, F0, c9a, 9, H, H);
    dapply<<<9, blk, 0, stream>>>(F0, c9a, wu1, wl1, bu1, bl1, F1, c9b, H);
    gemm_bias<<<gD9, blk, 0, stream>>>(F1, W1, b1, c9b, F0, c9a, 9, DIN, H);
    input_reduce<<<9, blk, 0, stream>>>(F0, c9a, u_in, l_in, out, DIN);
}

// Round 2
// 610.169 us; speedup vs baseline: 5.5069x; 5.5069x over previous
//
#include <hip/hip_runtime.h>
#include <math.h>

#define H 2048
#define DIN 784
#define DPAD 896   // DIN padded to multiple of 128

typedef unsigned short ushort_t;
typedef __attribute__((ext_vector_type(8))) short bf16x8;
typedef __attribute__((ext_vector_type(4))) float f32x4;

// ---------- helpers ----------
__device__ __forceinline__ float spu_f(float x){
    if (x >= 0.0f) return x*x - 0.5f;
    float s = 1.0f / (1.0f + __expf(x));   // sigmoid(-x)
    return s - 1.0f;
}
__device__ __forceinline__ float dspu_f(float x){
    if (x >= 0.0f) return 2.0f*x;
    float s = 1.0f / (1.0f + __expf(x));
    return -s * (1.0f - s);
}
__device__ __forceinline__ ushort_t f2bf(float x){
    unsigned u = __float_as_uint(x);
    unsigned r = (u + 0x7FFFu + ((u >> 16) & 1u)) >> 16;
    return (ushort_t)r;
}
__device__ __forceinline__ void load_lds16(const void* g, void* l){
    __builtin_amdgcn_global_load_lds((const __attribute__((address_space(1))) void*)g,
                                     (__attribute__((address_space(3))) void*)l,
                                     16, 0, 0);
}
__device__ __forceinline__ float block_reduce_256(float v, float* red){
    #pragma unroll
    for (int off = 32; off > 0; off >>= 1) v += __shfl_down(v, off, 64);
    int lane = threadIdx.x & 63, w = threadIdx.x >> 6;
    if (lane == 0) red[w] = v;
    __syncthreads();
    float t = 0.f;
    if (threadIdx.x == 0) t = red[0] + red[1] + red[2] + red[3];
    return t;   // valid on thread 0 only
}

// ---------- elementwise / reduction kernels ----------

// out[row] = c[row] + sum_{j<ncols} max(M,0)*pos_b + min(M,0)*neg_b   (M row stride = ld)
__global__ __launch_bounds__(256) void input_reduce(
    const float* __restrict__ M, const float* __restrict__ c,
    const float* __restrict__ pos_b, const float* __restrict__ neg_b,
    float* __restrict__ out, int ncols, int ld)
{
    __shared__ float red[4];
    int row = blockIdx.x;
    const float* Mr = M + (size_t)row * ld;
    float acc = 0.f;
    for (int j = threadIdx.x; j < ncols; j += 256){
        float v = Mr[j];
        acc += fmaxf(v, 0.f) * pos_b[j] + fminf(v, 0.f) * neg_b[j];
    }
    float t = block_reduce_256(acc, red);
    if (threadIdx.x == 0) out[row] = t + c[row];
}

// m_j = max(S,0)*w_pos + min(S,0)*w_neg ; Mout = bf16(m)
// c_out = c_in + sum_j [ max(S,0)*b_pos + min(S,0)*b_neg + m_j * bias_next[j] ]
__global__ __launch_bounds__(256) void dapply_bf16(
    const float* __restrict__ S, const float* __restrict__ c_in,
    const float* __restrict__ w_pos, const float* __restrict__ w_neg,
    const float* __restrict__ b_pos, const float* __restrict__ b_neg,
    const float* __restrict__ bias_next,
    ushort_t* __restrict__ Mout, float* __restrict__ c_out, int ncols)
{
    __shared__ float red[4];
    int row = blockIdx.x;
    const float* Sr = S + (size_t)row * ncols;
    ushort_t* Mr = Mout + (size_t)row * ncols;
    float acc = 0.f;
    for (int j = threadIdx.x; j < ncols; j += 256){
        float v = Sr[j];
        float p = fmaxf(v, 0.f), n = fminf(v, 0.f);
        float m = p * w_pos[j] + n * w_neg[j];
        Mr[j] = f2bf(m);
        acc += p * b_pos[j] + n * b_neg[j] + m * bias_next[j];
    }
    float t = block_reduce_256(acc, red);
    if (threadIdx.x == 0) c_out[row] = c_in[row] + t;
}

// fp32-output variant for the 9-row final chain
__global__ __launch_bounds__(256) void dapply_f32(
    const float* __restrict__ S, const float* __restrict__ c_in,
    const float* __restrict__ w_pos, const float* __restrict__ w_neg,
    const float* __restrict__ b_pos, const float* __restrict__ b_neg,
    const float* __restrict__ bias_next,
    float* __restrict__ Mout, float* __restrict__ c_out, int ncols)
{
    __shared__ float red[4];
    int row = blockIdx.x;
    const float* Sr = S + (size_t)row * ncols;
    float* Mr = Mout + (size_t)row * ncols;
    float acc = 0.f;
    for (int j = threadIdx.x; j < ncols; j += 256){
        float v = Sr[j];
        float p = fmaxf(v, 0.f), n = fminf(v, 0.f);
        float m = p * w_pos[j] + n * w_neg[j];
        Mr[j] = m;
        acc += p * b_pos[j] + n * b_neg[j] + m * bias_next[j];
    }
    float t = block_reduce_256(acc, red);
    if (threadIdx.x == 0) c_out[row] = c_in[row] + t;
}

// elementwise slope clip + intercepts
__global__ void spu_bounds(
    const float* __restrict__ lf, const float* __restrict__ uf,
    const float* __restrict__ pl, const float* __restrict__ pu,
    float* __restrict__ wl, float* __restrict__ wu,
    float* __restrict__ bl, float* __restrict__ bu, int n)
{
    int i = blockIdx.x * blockDim.x + threadIdx.x;
    if (i >= n) return;
    float l = lf[i], u = uf[i];
    float k1 = dspu_f(l), k2 = dspu_f(u);
    float klo = fminf(k1, k2), khi = fmaxf(k1, k2);
    float cwl = fminf(fmaxf(pl[i], klo), khi);
    float cwu = fminf(fmaxf(pu[i], klo), khi);
    float pts[4];
    pts[0] = l; pts[1] = u; pts[2] = 0.5f*(l+u); pts[3] = fminf(fmaxf(0.f, l), u);
    float bmin = INFINITY, bmax = -INFINITY;
    #pragma unroll
    for (int t = 0; t < 4; t++){
        float sp = spu_f(pts[t]);
        bmin = fminf(bmin, sp - cwl * pts[t]);
        bmax = fmaxf(bmax, sp - cwu * pts[t]);
    }
    wl[i] = cwl; wu[i] = cwu; bl[i] = bmin; bu[i] = bmax;
}

// F[r][j] = W4[k_r][j] - W4[tl][j];  c9[r] = b4[k_r] - b4[tl]; k_r = r + (r>=tl)
__global__ void final_init(const float* __restrict__ W4, const float* __restrict__ b4,
                           const int* __restrict__ tl_p,
                           float* __restrict__ F, float* __restrict__ c9)
{
    int tl = *tl_p;
    int idx = blockIdx.x * blockDim.x + threadIdx.x;
    if (idx >= 9 * H) return;
    int r = idx / H, j = idx % H;
    int k = r + (r >= tl ? 1 : 0);
    F[idx] = W4[(size_t)k * H + j] - W4[(size_t)tl * H + j];
    if (j == 0) c9[r] = b4[k] - b4[tl];
}

// fp32 [K][N] -> bf16 transposed [Npad][K]  (rows >= N zero-filled)
__global__ __launch_bounds__(256) void conv_transpose_bf16(
    const float* __restrict__ W, ushort_t* __restrict__ T,
    int K, int N, int Npad)
{
    __shared__ float tile[32][33];
    int n0 = blockIdx.x * 32, k0 = blockIdx.y * 32;
    int tx = threadIdx.x & 31;
    int ty = threadIdx.x >> 5;   // 0..7
    #pragma unroll
    for (int i = 0; i < 32; i += 8){
        int k = k0 + ty + i, n = n0 + tx;
        tile[ty + i][tx] = (k < K && n < N) ? W[(size_t)k * N + n] : 0.f;
    }
    __syncthreads();
    #pragma unroll
    for (int i = 0; i < 32; i += 8){
        int n = n0 + ty + i, k = k0 + tx;
        if (n < Npad && k < K) T[(size_t)n * K + k] = f2bf(tile[tx][ty + i]);
    }
}

// ---------- MFMA GEMM: C[M][N] = A[M][K] @ BT[N][K]^T  (bf16 in, fp32 out) ----------
// M,N multiples of 128; K multiple of 32. 256 threads, 4 waves, each wave 64x64.
#define TM 128
#define TN 128
#define TK 32
__global__ __launch_bounds__(256) void gemm_mfma(
    const ushort_t* __restrict__ A, const ushort_t* __restrict__ BT,
    float* __restrict__ C, int M, int N, int K)
{
    __shared__ ushort_t As[TM * TK];   // [128][32] row-major
    __shared__ ushort_t Bs[TN * TK];   // [128][32] (rows of BT)
    int tid  = threadIdx.x;
    int wave = tid >> 6, lane = tid & 63;
    int wm = (wave >> 1) * 64, wn = (wave & 1) * 64;
    int l16 = lane & 15, quad = lane >> 4;
    int row0 = blockIdx.y * TM, col0 = blockIdx.x * TN;

    // staging: e in [0,512), row = e>>2, kpart = e&3; lds elem off = e*8
    int r_lo = tid >> 2, kp = (tid & 3) * 8;
    const ushort_t* aSrc0 = A  + (size_t)(row0 + r_lo)      * K + kp;
    const ushort_t* aSrc1 = A  + (size_t)(row0 + 64 + r_lo) * K + kp;
    const ushort_t* bSrc0 = BT + (size_t)(col0 + r_lo)      * K + kp;
    const ushort_t* bSrc1 = BT + (size_t)(col0 + 64 + r_lo) * K + kp;
    ushort_t* aDst0 = As + wave * 512;           // wave-uniform, +lane*16B implicit
    ushort_t* aDst1 = As + 2048 + wave * 512;
    ushort_t* bDst0 = Bs + wave * 512;
    ushort_t* bDst1 = Bs + 2048 + wave * 512;

    f32x4 acc[4][4];
    #pragma unroll
    for (int i = 0; i < 4; i++)
        #pragma unroll
        for (int j = 0; j < 4; j++)
            acc[i][j] = (f32x4){0.f, 0.f, 0.f, 0.f};

    for (int k0 = 0; k0 < K; k0 += TK){
        load_lds16(aSrc0, aDst0);
        load_lds16(aSrc1, aDst1);
        load_lds16(bSrc0, bDst0);
        load_lds16(bSrc1, bDst1);
        aSrc0 += TK; aSrc1 += TK; bSrc0 += TK; bSrc1 += TK;
        __syncthreads();   // drains vmcnt (global_load_lds) + lgkm

        bf16x8 af[4], bfv[4];
        #pragma unroll
        for (int t = 0; t < 4; t++){
            af[t]  = *(const bf16x8*)&As[(wm + t*16 + l16) * TK + quad * 8];
            bfv[t] = *(const bf16x8*)&Bs[(wn + t*16 + l16) * TK + quad * 8];
        }
        #pragma unroll
        for (int i = 0; i < 4; i++)
            #pragma unroll
            for (int j = 0; j < 4; j++)
                acc[i][j] = __builtin_amdgcn_mfma_f32_16x16x32_bf16(af[i], bfv[j], acc[i][j], 0, 0, 0);
        __syncthreads();
    }

    // C/D layout: col = lane&15, row = quad*4 + reg   [verified m89/m91]
    #pragma unroll
    for (int i = 0; i < 4; i++){
        #pragma unroll
        for (int j = 0; j < 4; j++){
            int r0 = row0 + wm + i*16 + quad*4;
            int cc = col0 + wn + j*16 + l16;
            #pragma unroll
            for (int rr = 0; rr < 4; rr++)
                C[(size_t)(r0 + rr) * N + cc] = acc[i][j][rr];
        }
    }
}

// ---------- 9-row GEMV with K-split: C[9][N] += A[9][K] @ B[K][N] ----------
#define GK 128
__global__ __launch_bounds__(128) void gemv9(
    const float* __restrict__ A, const float* __restrict__ B,
    float* __restrict__ C, int K, int N)
{
    __shared__ float Alds[9 * GK];
    int k0 = blockIdx.y * GK;
    for (int t = threadIdx.x; t < 9 * GK; t += 128){
        int r = t / GK, kk = t - r * GK;
        Alds[t] = A[(size_t)r * K + k0 + kk];
    }
    __syncthreads();
    int j = blockIdx.x * 128 + threadIdx.x;
    if (j >= N) return;
    float acc[9] = {0.f,0.f,0.f,0.f,0.f,0.f,0.f,0.f,0.f};
    for (int kk = 0; kk < GK; kk++){
        float b = B[(size_t)(k0 + kk) * N + j];
        #pragma unroll
        for (int r = 0; r < 9; r++) acc[r] += Alds[r * GK + kk] * b;
    }
    #pragma unroll
    for (int r = 0; r < 9; r++) atomicAdd(&C[(size_t)r * N + j], acc[r]);
}

extern "C" void kernel_launch(void* const* d_in, const int* in_sizes, int n_in,
                              void* d_out, int out_size, void* d_ws, size_t ws_size,
                              hipStream_t stream)
{
    const float* W1  = (const float*)d_in[0];
    const float* b1  = (const float*)d_in[1];
    const float* W2  = (const float*)d_in[2];
    const float* b2  = (const float*)d_in[3];
    const float* W3  = (const float*)d_in[4];
    const float* b3  = (const float*)d_in[5];
    const float* W4  = (const float*)d_in[6];
    const float* b4  = (const float*)d_in[7];
    const float* l_in = (const float*)d_in[8];
    const float* u_in = (const float*)d_in[9];
    const float* p_l1 = (const float*)d_in[10];
    const float* p_u1 = (const float*)d_in[11];
    const float* p_l2 = (const float*)d_in[12];
    const float* p_u2 = (const float*)d_in[13];
    const float* p_l3 = (const float*)d_in[14];
    const float* p_u3 = (const float*)d_in[15];
    const int*   tl   = (const int*)d_in[16];
    float* out = (float*)d_out;

    // workspace layout (256-B aligned chunks)
    size_t off = 0;
    auto allocB = [&](size_t bytes) -> void* {
        void* p = (char*)d_ws + off;
        off += (bytes + 255) & ~(size_t)255;
        return p;
    };
    ushort_t* W1bt  = (ushort_t*)allocB((size_t)DPAD * H * 2);  // [896][2048] bf16
    ushort_t* W2bt  = (ushort_t*)allocB((size_t)H * H * 2);     // [2048][2048] bf16
    ushort_t* Abf_l = (ushort_t*)allocB((size_t)H * H * 2);
    ushort_t* Abf_u = (ushort_t*)allocB((size_t)H * H * 2);
    float* B_l = (float*)allocB((size_t)H * H * 4);
    float* B_u = (float*)allocB((size_t)H * H * 4);
    float* lf  = (float*)allocB(H * 4);
    float* uf  = (float*)allocB(H * 4);
    float *wl1=(float*)allocB(H*4), *wu1=(float*)allocB(H*4), *bl1=(float*)allocB(H*4), *bu1=(float*)allocB(H*4);
    float *wl2=(float*)allocB(H*4), *wu2=(float*)allocB(H*4), *bl2=(float*)allocB(H*4), *bu2=(float*)allocB(H*4);
    float *wl3=(float*)allocB(H*4), *wu3=(float*)allocB(H*4), *bl3=(float*)allocB(H*4), *bu3=(float*)allocB(H*4);
    float *cl_a=(float*)allocB(H*4), *cl_b=(float*)allocB(H*4);
    float *cu_a=(float*)allocB(H*4), *cu_b=(float*)allocB(H*4);
    float* F0  = (float*)allocB(9 * H * 4);
    float* F1  = (float*)allocB(9 * H * 4);
    float *c9a=(float*)allocB(64), *c9b=(float*)allocB(64);

    dim3 blk(256);

    // ---- weight conversion (bf16, transposed, padded) ----
    conv_transpose_bf16<<<dim3(DPAD/32, H/32), blk, 0, stream>>>(W1, W1bt, H, DIN, DPAD);
    conv_transpose_bf16<<<dim3(H/32,   H/32), blk, 0, stream>>>(W2, W2bt, H, H, H);

    // ---- stage 1: layer-1 pre-activation bounds ----
    input_reduce<<<H, blk, 0, stream>>>(W1, b1, l_in, u_in, lf, DIN, DIN);
    input_reduce<<<H, blk, 0, stream>>>(W1, b1, u_in, l_in, uf, DIN, DIN);
    spu_bounds<<<(H + 255)/256, blk, 0, stream>>>(lf, uf, p_l1, p_u1, wl1, wu1, bl1, bu1, H);

    dim3 gNN(H/TN, H/TM);      // 2048x2048
    dim3 gND(DPAD/TN, H/TM);   // 2048x896

    // ---- stage 2: (W2,b2) -> D1 -> @W1 -> input ----
    dapply_bf16<<<H, blk, 0, stream>>>(W2, b2, wl1, wu1, bl1, bu1, b1, Abf_l, cl_a, H);
    dapply_bf16<<<H, blk, 0, stream>>>(W2, b2, wu1, wl1, bu1, bl1, b1, Abf_u, cu_a, H);
    gemm_mfma<<<gND, blk, 0, stream>>>(Abf_l, W1bt, B_l, H, DPAD, H);
    gemm_mfma<<<gND, blk, 0, stream>>>(Abf_u, W1bt, B_u, H, DPAD, H);
    input_reduce<<<H, blk, 0, stream>>>(B_l, cl_a, l_in, u_in, lf, DIN, DPAD);
    input_reduce<<<H, blk, 0, stream>>>(B_u, cu_a, u_in, l_in, uf, DIN, DPAD);
    spu_bounds<<<(H + 255)/256, blk, 0, stream>>>(lf, uf, p_l2, p_u2, wl2, wu2, bl2, bu2, H);

    // ---- stage 3: (W3,b3) -> D2 -> @W2 -> D1 -> @W1 -> input ----
    dapply_bf16<<<H, blk, 0, stream>>>(W3, b3, wl2, wu2, bl2, bu2, b2, Abf_l, cl_a, H);
    dapply_bf16<<<H, blk, 0, stream>>>(W3, b3, wu2, wl2, bu2, bl2, b2, Abf_u, cu_a, H);
    gemm_mfma<<<gNN, blk, 0, stream>>>(Abf_l, W2bt, B_l, H, H, H);
    gemm_mfma<<<gNN, blk, 0, stream>>>(Abf_u, W2bt, B_u, H, H, H);
    dapply_bf16<<<H, blk, 0, stream>>>(B_l, cl_a, wl1, wu1, bl1, bu1, b1, Abf_l, cl_b, H);
    dapply_bf16<<<H, blk, 0, stream>>>(B_u, cu_a, wu1, wl1, bu1, bl1, b1, Abf_u, cu_b, H);
    gemm_mfma<<<gND, blk, 0, stream>>>(Abf_l, W1bt, B_l, H, DPAD, H);
    gemm_mfma<<<gND, blk, 0, stream>>>(Abf_u, W1bt, B_u, H, DPAD, H);
    input_reduce<<<H, blk, 0, stream>>>(B_l, cl_b, l_in, u_in, lf, DIN, DPAD);
    input_reduce<<<H, blk, 0, stream>>>(B_u, cu_b, u_in, l_in, uf, DIN, DPAD);
    spu_bounds<<<(H + 255)/256, blk, 0, stream>>>(lf, uf, p_l3, p_u3, wl3, wu3, bl3, bu3, H);

    // ---- final chain (upper bound only), 9 rows, fp32 ----
    final_init<<<(9*H + 255)/256, blk, 0, stream>>>(W4, b4, tl, F0, c9a);

    dapply_f32<<<9, blk, 0, stream>>>(F0, c9a, wu3, wl3, bu3, bl3, b3, F1, c9b, H);
    hipMemsetAsync(F0, 0, (size_t)9 * H * 4, stream);
    gemv9<<<dim3(H/128, H/GK), dim3(128), 0, stream>>>(F1, W3, F0, H, H);

    dapply_f32<<<9, blk, 0, stream>>>(F0, c9b, wu2, wl2, bu2, bl2, b2, F1, c9a, H);
    hipMemsetAsync(F0, 0, (size_t)9 * H * 4, stream);
    gemv9<<<dim3(H/128, H/GK), dim3(128), 0, stream>>>(F1, W2, F0, H, H);

    dapply_f32<<<9, blk, 0, stream>>>(F0, c9a, wu1, wl1, bu1, bl1, b1, F1, c9b, H);
    hipMemsetAsync(F0, 0, (size_t)9 * DIN * 4, stream);
    gemv9<<<dim3((DIN + 127)/128, H/GK), dim3(128), 0, stream>>>(F1, W1, F0, H, DIN);

    input_reduce<<<9, blk, 0, stream>>>(F0, c9b, u_in, l_in, out, DIN, DIN);
}

// Round 3
// 473.922 us; speedup vs baseline: 7.0901x; 1.2875x over previous
//
#include <hip/hip_runtime.h>
#include <math.h>

#define H 2048
#define DIN 784
#define DPAD 896   // DIN padded to multiple of 128

typedef unsigned short ushort_t;
typedef __attribute__((ext_vector_type(8))) short bf16x8;
typedef __attribute__((ext_vector_type(4))) float f32x4;

// ---------- helpers ----------
__device__ __forceinline__ float spu_f(float x){
    if (x >= 0.0f) return x*x - 0.5f;
    float s = 1.0f / (1.0f + __expf(x));   // sigmoid(-x)
    return s - 1.0f;
}
__device__ __forceinline__ float dspu_f(float x){
    if (x >= 0.0f) return 2.0f*x;
    float s = 1.0f / (1.0f + __expf(x));
    return -s * (1.0f - s);
}
__device__ __forceinline__ ushort_t f2bf(float x){
    unsigned u = __float_as_uint(x);
    unsigned r = (u + 0x7FFFu + ((u >> 16) & 1u)) >> 16;
    return (ushort_t)r;
}
__device__ __forceinline__ void load_lds16(const void* g, void* l){
    __builtin_amdgcn_global_load_lds((const __attribute__((address_space(1))) void*)g,
                                     (__attribute__((address_space(3))) void*)l,
                                     16, 0, 0);
}
__device__ __forceinline__ float block_reduce_256(float v, float* red){
    #pragma unroll
    for (int off = 32; off > 0; off >>= 1) v += __shfl_down(v, off, 64);
    int lane = threadIdx.x & 63, w = threadIdx.x >> 6;
    if (lane == 0) red[w] = v;
    __syncthreads();
    float t = 0.f;
    if (threadIdx.x == 0) t = red[0] + red[1] + red[2] + red[3];
    return t;   // valid on thread 0 only
}
// two simultaneous block reductions; outputs valid on thread 0
__device__ __forceinline__ void block_reduce2_256(float vl, float vu, float* red,
                                                  float& out_l, float& out_u){
    #pragma unroll
    for (int off = 32; off > 0; off >>= 1){
        vl += __shfl_down(vl, off, 64);
        vu += __shfl_down(vu, off, 64);
    }
    int lane = threadIdx.x & 63, w = threadIdx.x >> 6;
    if (lane == 0){ red[w] = vl; red[4 + w] = vu; }
    __syncthreads();
    if (threadIdx.x == 0){
        out_l = red[0] + red[1] + red[2] + red[3];
        out_u = red[4] + red[5] + red[6] + red[7];
    }
}

// ---------- fused bound + SPU-relaxation kernel ----------
// Per row r: l = c_l[r] + sum_j mix(M_l[r][j]; l_in,u_in)
//            u = c_u[r] + sum_j mix(M_u[r][j]; u_in,l_in)
// then slope clip + intercepts for SPU, written to wl/wu/bl/bu[r].
// same!=0 means M_l==M_u (read once).
__global__ __launch_bounds__(256) void bounds_fused(
    const float* __restrict__ M_l, const float* __restrict__ M_u,
    const float* __restrict__ c_l, const float* __restrict__ c_u,
    const float* __restrict__ l_in, const float* __restrict__ u_in,
    const float* __restrict__ pl, const float* __restrict__ pu,
    float* __restrict__ wl, float* __restrict__ wu,
    float* __restrict__ bl, float* __restrict__ bu,
    int ncols, int ld, int same)
{
    __shared__ float red[8];
    int row = blockIdx.x;
    const float* Ml = M_l + (size_t)row * ld;
    const float* Mu = M_u + (size_t)row * ld;
    float accl = 0.f, accu = 0.f;
    if (same){
        for (int j = threadIdx.x; j < ncols; j += 256){
            float v = Ml[j];
            float p = fmaxf(v, 0.f), n = fminf(v, 0.f);
            accl += p * l_in[j] + n * u_in[j];
            accu += p * u_in[j] + n * l_in[j];
        }
    } else {
        for (int j = threadIdx.x; j < ncols; j += 256){
            float vl = Ml[j], vu = Mu[j];
            accl += fmaxf(vl, 0.f) * l_in[j] + fminf(vl, 0.f) * u_in[j];
            accu += fmaxf(vu, 0.f) * u_in[j] + fminf(vu, 0.f) * l_in[j];
        }
    }
    float tl, tu;
    block_reduce2_256(accl, accu, red, tl, tu);
    if (threadIdx.x == 0){
        float l = tl + c_l[row];
        float u = tu + c_u[row];
        float k1 = dspu_f(l), k2 = dspu_f(u);
        float klo = fminf(k1, k2), khi = fmaxf(k1, k2);
        float cwl = fminf(fmaxf(pl[row], klo), khi);
        float cwu = fminf(fmaxf(pu[row], klo), khi);
        float pts[4];
        pts[0] = l; pts[1] = u; pts[2] = 0.5f*(l+u); pts[3] = fminf(fmaxf(0.f, l), u);
        float bmin = INFINITY, bmax = -INFINITY;
        #pragma unroll
        for (int t = 0; t < 4; t++){
            float sp = spu_f(pts[t]);
            bmin = fminf(bmin, sp - cwl * pts[t]);
            bmax = fmaxf(bmax, sp - cwu * pts[t]);
        }
        wl[row] = cwl; wu[row] = cwu; bl[row] = bmin; bu[row] = bmax;
    }
}

// ---------- dapply: stage-start dual (S shared by l and u) ----------
__global__ __launch_bounds__(256) void dapply_dual(
    const float* __restrict__ S, const float* __restrict__ c_in,
    const float* __restrict__ wl, const float* __restrict__ wu,
    const float* __restrict__ bl, const float* __restrict__ bu,
    const float* __restrict__ bias_next,
    ushort_t* __restrict__ Ml, ushort_t* __restrict__ Mu,
    float* __restrict__ cl_out, float* __restrict__ cu_out, int ncols)
{
    __shared__ float red[8];
    int row = blockIdx.x;
    const float* Sr = S + (size_t)row * ncols;
    ushort_t* Mlr = Ml + (size_t)row * ncols;
    ushort_t* Mur = Mu + (size_t)row * ncols;
    float accl = 0.f, accu = 0.f;
    for (int j = threadIdx.x; j < ncols; j += 256){
        float v = Sr[j];
        float p = fmaxf(v, 0.f), n = fminf(v, 0.f);
        float wlj = wl[j], wuj = wu[j], blj = bl[j], buj = bu[j], bn = bias_next[j];
        float ml = p * wlj + n * wuj;
        float mu = p * wuj + n * wlj;
        Mlr[j] = f2bf(ml);
        Mur[j] = f2bf(mu);
        accl += p * blj + n * buj + ml * bn;
        accu += p * buj + n * blj + mu * bn;
    }
    float tl, tu;
    block_reduce2_256(accl, accu, red, tl, tu);
    if (threadIdx.x == 0){
        float c = c_in[row];
        cl_out[row] = c + tl;
        cu_out[row] = c + tu;
    }
}

// ---------- dapply: mid-stage pair (separate S_l,S_u), blockIdx.y = lu ----------
__global__ __launch_bounds__(256) void dapply_pair(
    const float* __restrict__ S_l, const float* __restrict__ S_u,
    const float* __restrict__ cl_in, const float* __restrict__ cu_in,
    const float* __restrict__ wl, const float* __restrict__ wu,
    const float* __restrict__ bl, const float* __restrict__ bu,
    const float* __restrict__ bias_next,
    ushort_t* __restrict__ Ml, ushort_t* __restrict__ Mu,
    float* __restrict__ cl_out, float* __restrict__ cu_out, int ncols)
{
    __shared__ float red[4];
    int row = blockIdx.x;
    int lu = blockIdx.y;
    const float* Sr = (lu ? S_u : S_l) + (size_t)row * ncols;
    const float* w_pos = lu ? wu : wl;
    const float* w_neg = lu ? wl : wu;
    const float* b_pos = lu ? bu : bl;
    const float* b_neg = lu ? bl : bu;
    ushort_t* Mr = (lu ? Mu : Ml) + (size_t)row * ncols;
    float acc = 0.f;
    for (int j = threadIdx.x; j < ncols; j += 256){
        float v = Sr[j];
        float p = fmaxf(v, 0.f), n = fminf(v, 0.f);
        float m = p * w_pos[j] + n * w_neg[j];
        Mr[j] = f2bf(m);
        acc += p * b_pos[j] + n * b_neg[j] + m * bias_next[j];
    }
    float t = block_reduce_256(acc, red);
    if (threadIdx.x == 0){
        if (lu) cu_out[row] = cu_in[row] + t;
        else    cl_out[row] = cl_in[row] + t;
    }
}

// fp32-output dapply for the 9-row final chain
__global__ __launch_bounds__(256) void dapply_f32(
    const float* __restrict__ S, const float* __restrict__ c_in,
    const float* __restrict__ w_pos, const float* __restrict__ w_neg,
    const float* __restrict__ b_pos, const float* __restrict__ b_neg,
    const float* __restrict__ bias_next,
    float* __restrict__ Mout, float* __restrict__ c_out, int ncols)
{
    __shared__ float red[4];
    int row = blockIdx.x;
    const float* Sr = S + (size_t)row * ncols;
    float* Mr = Mout + (size_t)row * ncols;
    float acc = 0.f;
    for (int j = threadIdx.x; j < ncols; j += 256){
        float v = Sr[j];
        float p = fmaxf(v, 0.f), n = fminf(v, 0.f);
        float m = p * w_pos[j] + n * w_neg[j];
        Mr[j] = m;
        acc += p * b_pos[j] + n * b_neg[j] + m * bias_next[j];
    }
    float t = block_reduce_256(acc, red);
    if (threadIdx.x == 0) c_out[row] = c_in[row] + t;
}

// final output: out[row] = c[row] + sum_j mix(M[row][j]; pos_b,neg_b)
__global__ __launch_bounds__(256) void input_reduce(
    const float* __restrict__ M, const float* __restrict__ c,
    const float* __restrict__ pos_b, const float* __restrict__ neg_b,
    float* __restrict__ out, int ncols, int ld)
{
    __shared__ float red[4];
    int row = blockIdx.x;
    const float* Mr = M + (size_t)row * ld;
    float acc = 0.f;
    for (int j = threadIdx.x; j < ncols; j += 256){
        float v = Mr[j];
        acc += fmaxf(v, 0.f) * pos_b[j] + fminf(v, 0.f) * neg_b[j];
    }
    float t = block_reduce_256(acc, red);
    if (threadIdx.x == 0) out[row] = t + c[row];
}

// F[r][j] = W4[k_r][j] - W4[tl][j];  c9[r] = b4[k_r] - b4[tl]; k_r = r + (r>=tl)
__global__ void final_init(const float* __restrict__ W4, const float* __restrict__ b4,
                           const int* __restrict__ tl_p,
                           float* __restrict__ F, float* __restrict__ c9)
{
    int tl = *tl_p;
    int idx = blockIdx.x * blockDim.x + threadIdx.x;
    if (idx >= 9 * H) return;
    int r = idx / H, j = idx % H;
    int k = r + (r >= tl ? 1 : 0);
    F[idx] = W4[(size_t)k * H + j] - W4[(size_t)tl * H + j];
    if (j == 0) c9[r] = b4[k] - b4[tl];
}

// fp32 [K][N] -> bf16 transposed [Npad][K]  (rows >= N zero-filled)
__global__ __launch_bounds__(256) void conv_transpose_bf16(
    const float* __restrict__ W, ushort_t* __restrict__ T,
    int K, int N, int Npad)
{
    __shared__ float tile[32][33];
    int n0 = blockIdx.x * 32, k0 = blockIdx.y * 32;
    int tx = threadIdx.x & 31;
    int ty = threadIdx.x >> 5;   // 0..7
    #pragma unroll
    for (int i = 0; i < 32; i += 8){
        int k = k0 + ty + i, n = n0 + tx;
        tile[ty + i][tx] = (k < K && n < N) ? W[(size_t)k * N + n] : 0.f;
    }
    __syncthreads();
    #pragma unroll
    for (int i = 0; i < 32; i += 8){
        int n = n0 + ty + i, k = k0 + tx;
        if (n < Npad && k < K) T[(size_t)n * K + k] = f2bf(tile[tx][ty + i]);
    }
}

// ---------- MFMA GEMM pair: C_{l,u}[M][N] (+)= A_{l,u}[M][K] @ BT[N][K]^T ----------
// blockIdx.z = lu*ksplit + ks. ksplit>1 => atomicAdd epilogue (C pre-zeroed).
#define TM 128
#define TN 128
#define TK 32
__global__ __launch_bounds__(256) void gemm_mfma_pair(
    const ushort_t* __restrict__ A_l, const ushort_t* __restrict__ A_u,
    const ushort_t* __restrict__ BT,
    float* __restrict__ C_l, float* __restrict__ C_u,
    int M, int N, int K, int ksplit)
{
    __shared__ ushort_t As[TM * TK];   // [128][32] row-major
    __shared__ ushort_t Bs[TN * TK];
    int z = blockIdx.z;
    int lu = z / ksplit, ks = z - lu * ksplit;
    const ushort_t* A = lu ? A_u : A_l;
    float* C = lu ? C_u : C_l;
    int Kpart = K / ksplit;
    int kbeg = ks * Kpart;

    int tid  = threadIdx.x;
    int wave = tid >> 6, lane = tid & 63;
    int wm = (wave >> 1) * 64, wn = (wave & 1) * 64;
    int l16 = lane & 15, quad = lane >> 4;
    int row0 = blockIdx.y * TM, col0 = blockIdx.x * TN;

    int r_lo = tid >> 2, kp = (tid & 3) * 8;
    const ushort_t* aSrc0 = A  + (size_t)(row0 + r_lo)      * K + kbeg + kp;
    const ushort_t* aSrc1 = A  + (size_t)(row0 + 64 + r_lo) * K + kbeg + kp;
    const ushort_t* bSrc0 = BT + (size_t)(col0 + r_lo)      * K + kbeg + kp;
    const ushort_t* bSrc1 = BT + (size_t)(col0 + 64 + r_lo) * K + kbeg + kp;
    ushort_t* aDst0 = As + wave * 512;
    ushort_t* aDst1 = As + 2048 + wave * 512;
    ushort_t* bDst0 = Bs + wave * 512;
    ushort_t* bDst1 = Bs + 2048 + wave * 512;

    f32x4 acc[4][4];
    #pragma unroll
    for (int i = 0; i < 4; i++)
        #pragma unroll
        for (int j = 0; j < 4; j++)
            acc[i][j] = (f32x4){0.f, 0.f, 0.f, 0.f};

    for (int kk0 = 0; kk0 < Kpart; kk0 += TK){
        load_lds16(aSrc0, aDst0);
        load_lds16(aSrc1, aDst1);
        load_lds16(bSrc0, bDst0);
        load_lds16(bSrc1, bDst1);
        aSrc0 += TK; aSrc1 += TK; bSrc0 += TK; bSrc1 += TK;
        __syncthreads();

        bf16x8 af[4], bfv[4];
        #pragma unroll
        for (int t = 0; t < 4; t++){
            af[t]  = *(const bf16x8*)&As[(wm + t*16 + l16) * TK + quad * 8];
            bfv[t] = *(const bf16x8*)&Bs[(wn + t*16 + l16) * TK + quad * 8];
        }
        #pragma unroll
        for (int i = 0; i < 4; i++)
            #pragma unroll
            for (int j = 0; j < 4; j++)
                acc[i][j] = __builtin_amdgcn_mfma_f32_16x16x32_bf16(af[i], bfv[j], acc[i][j], 0, 0, 0);
        __syncthreads();
    }

    // C/D layout: col = lane&15, row = quad*4 + reg
    #pragma unroll
    for (int i = 0; i < 4; i++){
        #pragma unroll
        for (int j = 0; j < 4; j++){
            int r0 = row0 + wm + i*16 + quad*4;
            int cc = col0 + wn + j*16 + l16;
            if (ksplit > 1){
                #pragma unroll
                for (int rr = 0; rr < 4; rr++)
                    atomicAdd(&C[(size_t)(r0 + rr) * N + cc], acc[i][j][rr]);
            } else {
                #pragma unroll
                for (int rr = 0; rr < 4; rr++)
                    C[(size_t)(r0 + rr) * N + cc] = acc[i][j][rr];
            }
        }
    }
}

// ---------- 9-row GEMV with K-split ----------
#define GK 128
__global__ __launch_bounds__(128) void gemv9(
    const float* __restrict__ A, const float* __restrict__ B,
    float* __restrict__ C, int K, int N)
{
    __shared__ float Alds[9 * GK];
    int k0 = blockIdx.y * GK;
    for (int t = threadIdx.x; t < 9 * GK; t += 128){
        int r = t / GK, kk = t - r * GK;
        Alds[t] = A[(size_t)r * K + k0 + kk];
    }
    __syncthreads();
    int j = blockIdx.x * 128 + threadIdx.x;
    if (j >= N) return;
    float acc[9] = {0.f,0.f,0.f,0.f,0.f,0.f,0.f,0.f,0.f};
    for (int kk = 0; kk < GK; kk++){
        float b = B[(size_t)(k0 + kk) * N + j];
        #pragma unroll
        for (int r = 0; r < 9; r++) acc[r] += Alds[r * GK + kk] * b;
    }
    #pragma unroll
    for (int r = 0; r < 9; r++) atomicAdd(&C[(size_t)r * N + j], acc[r]);
}

extern "C" void kernel_launch(void* const* d_in, const int* in_sizes, int n_in,
                              void* d_out, int out_size, void* d_ws, size_t ws_size,
                              hipStream_t stream)
{
    const float* W1  = (const float*)d_in[0];
    const float* b1  = (const float*)d_in[1];
    const float* W2  = (const float*)d_in[2];
    const float* b2  = (const float*)d_in[3];
    const float* W3  = (const float*)d_in[4];
    const float* b3  = (const float*)d_in[5];
    const float* W4  = (const float*)d_in[6];
    const float* b4  = (const float*)d_in[7];
    const float* l_in = (const float*)d_in[8];
    const float* u_in = (const float*)d_in[9];
    const float* p_l1 = (const float*)d_in[10];
    const float* p_u1 = (const float*)d_in[11];
    const float* p_l2 = (const float*)d_in[12];
    const float* p_u2 = (const float*)d_in[13];
    const float* p_l3 = (const float*)d_in[14];
    const float* p_u3 = (const float*)d_in[15];
    const int*   tl   = (const int*)d_in[16];
    float* out = (float*)d_out;

    size_t off = 0;
    auto allocB = [&](size_t bytes) -> void* {
        void* p = (char*)d_ws + off;
        off += (bytes + 255) & ~(size_t)255;
        return p;
    };
    ushort_t* W1bt  = (ushort_t*)allocB((size_t)DPAD * H * 2);
    ushort_t* W2bt  = (ushort_t*)allocB((size_t)H * H * 2);
    ushort_t* Abf_l = (ushort_t*)allocB((size_t)H * H * 2);
    ushort_t* Abf_u = (ushort_t*)allocB((size_t)H * H * 2);
    float* B_l = (float*)allocB((size_t)H * H * 4);
    float* B_u = (float*)allocB((size_t)H * H * 4);
    float *wl1=(float*)allocB(H*4), *wu1=(float*)allocB(H*4), *bl1=(float*)allocB(H*4), *bu1=(float*)allocB(H*4);
    float *wl2=(float*)allocB(H*4), *wu2=(float*)allocB(H*4), *bl2=(float*)allocB(H*4), *bu2=(float*)allocB(H*4);
    float *wl3=(float*)allocB(H*4), *wu3=(float*)allocB(H*4), *bl3=(float*)allocB(H*4), *bu3=(float*)allocB(H*4);
    float *cl_a=(float*)allocB(H*4), *cl_b=(float*)allocB(H*4);
    float *cu_a=(float*)allocB(H*4), *cu_b=(float*)allocB(H*4);
    float* F0  = (float*)allocB(9 * H * 4);
    float* F1  = (float*)allocB(9 * H * 4);
    float *c9a=(float*)allocB(64), *c9b=(float*)allocB(64);

    dim3 blk(256);
    dim3 gNN(H/TN,    H/TM, 2);   // l/u pair, no K-split
    dim3 gND(DPAD/TN, H/TM, 4);   // l/u pair x K-split 2

    // ---- weight conversion ----
    conv_transpose_bf16<<<dim3(DPAD/32, H/32), blk, 0, stream>>>(W1, W1bt, H, DIN, DPAD);
    conv_transpose_bf16<<<dim3(H/32,   H/32), blk, 0, stream>>>(W2, W2bt, H, H, H);

    // ---- stage 1: bounds of layer-1 pre-activations (M_l == M_u == W1) ----
    bounds_fused<<<H, blk, 0, stream>>>(W1, W1, b1, b1, l_in, u_in, p_l1, p_u1,
                                        wl1, wu1, bl1, bu1, DIN, DIN, 1);

    // ---- stage 2: (W2,b2) -> D1 -> @W1 -> bounds ----
    dapply_dual<<<H, blk, 0, stream>>>(W2, b2, wl1, wu1, bl1, bu1, b1,
                                       Abf_l, Abf_u, cl_a, cu_a, H);
    hipMemsetAsync(B_l, 0, (size_t)H * DPAD * 4, stream);
    hipMemsetAsync(B_u, 0, (size_t)H * DPAD * 4, stream);
    gemm_mfma_pair<<<gND, blk, 0, stream>>>(Abf_l, Abf_u, W1bt, B_l, B_u, H, DPAD, H, 2);
    bounds_fused<<<H, blk, 0, stream>>>(B_l, B_u, cl_a, cu_a, l_in, u_in, p_l2, p_u2,
                                        wl2, wu2, bl2, bu2, DIN, DPAD, 0);

    // ---- stage 3: (W3,b3) -> D2 -> @W2 -> D1 -> @W1 -> bounds ----
    dapply_dual<<<H, blk, 0, stream>>>(W3, b3, wl2, wu2, bl2, bu2, b2,
                                       Abf_l, Abf_u, cl_a, cu_a, H);
    gemm_mfma_pair<<<gNN, blk, 0, stream>>>(Abf_l, Abf_u, W2bt, B_l, B_u, H, H, H, 1);
    dapply_pair<<<dim3(H, 2), blk, 0, stream>>>(B_l, B_u, cl_a, cu_a,
                                                wl1, wu1, bl1, bu1, b1,
                                                Abf_l, Abf_u, cl_b, cu_b, H);
    hipMemsetAsync(B_l, 0, (size_t)H * DPAD * 4, stream);
    hipMemsetAsync(B_u, 0, (size_t)H * DPAD * 4, stream);
    gemm_mfma_pair<<<gND, blk, 0, stream>>>(Abf_l, Abf_u, W1bt, B_l, B_u, H, DPAD, H, 2);
    bounds_fused<<<H, blk, 0, stream>>>(B_l, B_u, cl_b, cu_b, l_in, u_in, p_l3, p_u3,
                                        wl3, wu3, bl3, bu3, DIN, DPAD, 0);

    // ---- final chain (upper bound only), 9 rows, fp32 ----
    final_init<<<(9*H + 255)/256, blk, 0, stream>>>(W4, b4, tl, F0, c9a);

    dapply_f32<<<9, blk, 0, stream>>>(F0, c9a, wu3, wl3, bu3, bl3, b3, F1, c9b, H);
    hipMemsetAsync(F0, 0, (size_t)9 * H * 4, stream);
    gemv9<<<dim3(H/128, H/GK), dim3(128), 0, stream>>>(F1, W3, F0, H, H);

    dapply_f32<<<9, blk, 0, stream>>>(F0, c9b, wu2, wl2, bu2, bl2, b2, F1, c9a, H);
    hipMemsetAsync(F0, 0, (size_t)9 * H * 4, stream);
    gemv9<<<dim3(H/128, H/GK), dim3(128), 0, stream>>>(F1, W2, F0, H, H);

    dapply_f32<<<9, blk, 0, stream>>>(F0, c9a, wu1, wl1, bu1, bl1, b1, F1, c9b, H);
    hipMemsetAsync(F0, 0, (size_t)9 * DIN * 4, stream);
    gemv9<<<dim3((DIN + 127)/128, H/GK), dim3(128), 0, stream>>>(F1, W1, F0, H, DIN);

    input_reduce<<<9, blk, 0, stream>>>(F0, c9b, u_in, l_in, out, DIN, DIN);
}

// Round 4
// 413.794 us; speedup vs baseline: 8.1204x; 1.1453x over previous
//
#include <hip/hip_runtime.h>
#include <math.h>

#define H 2048
#define DIN 784
#define DPAD 896   // DIN padded to multiple of 128

typedef unsigned short ushort_t;
typedef __attribute__((ext_vector_type(8))) short bf16x8;
typedef __attribute__((ext_vector_type(4))) float f32x4;

// ---------- helpers ----------
__device__ __forceinline__ float spu_f(float x){
    if (x >= 0.0f) return x*x - 0.5f;
    float s = 1.0f / (1.0f + __expf(x));   // sigmoid(-x)
    return s - 1.0f;
}
__device__ __forceinline__ float dspu_f(float x){
    if (x >= 0.0f) return 2.0f*x;
    float s = 1.0f / (1.0f + __expf(x));
    return -s * (1.0f - s);
}
__device__ __forceinline__ ushort_t f2bf(float x){
    unsigned u = __float_as_uint(x);
    unsigned r = (u + 0x7FFFu + ((u >> 16) & 1u)) >> 16;
    return (ushort_t)r;
}
__device__ __forceinline__ void load_lds16(const void* g, void* l){
    __builtin_amdgcn_global_load_lds((const __attribute__((address_space(1))) void*)g,
                                     (__attribute__((address_space(3))) void*)l,
                                     16, 0, 0);
}
__device__ __forceinline__ float block_reduce_256(float v, float* red){
    #pragma unroll
    for (int off = 32; off > 0; off >>= 1) v += __shfl_down(v, off, 64);
    int lane = threadIdx.x & 63, w = threadIdx.x >> 6;
    if (lane == 0) red[w] = v;
    __syncthreads();
    float t = 0.f;
    if (threadIdx.x == 0) t = red[0] + red[1] + red[2] + red[3];
    return t;   // valid on thread 0 only
}
__device__ __forceinline__ void block_reduce2_256(float vl, float vu, float* red,
                                                  float& out_l, float& out_u){
    #pragma unroll
    for (int off = 32; off > 0; off >>= 1){
        vl += __shfl_down(vl, off, 64);
        vu += __shfl_down(vu, off, 64);
    }
    int lane = threadIdx.x & 63, w = threadIdx.x >> 6;
    if (lane == 0){ red[w] = vl; red[4 + w] = vu; }
    __syncthreads();
    if (threadIdx.x == 0){
        out_l = red[0] + red[1] + red[2] + red[3];
        out_u = red[4] + red[5] + red[6] + red[7];
    }
}

// ---------- fused bound + SPU-relaxation ----------
// pstride!=0: M rows are sums of two partial buffers (M[j] + M[j+pstride]).
// same!=0: M_l == M_u (read once).
__global__ __launch_bounds__(256) void bounds_fused(
    const float* __restrict__ M_l, const float* __restrict__ M_u,
    const float* __restrict__ c_l, const float* __restrict__ c_u,
    const float* __restrict__ l_in, const float* __restrict__ u_in,
    const float* __restrict__ pl, const float* __restrict__ pu,
    float* __restrict__ wl, float* __restrict__ wu,
    float* __restrict__ bl, float* __restrict__ bu,
    int ncols, int ld, size_t pstride, int same)
{
    __shared__ float red[8];
    int row = blockIdx.x;
    const float* Ml = M_l + (size_t)row * ld;
    const float* Mu = M_u + (size_t)row * ld;
    float accl = 0.f, accu = 0.f;
    if (pstride){
        for (int j = threadIdx.x; j < ncols; j += 256){
            float vl = Ml[j] + Ml[j + pstride];
            float vu = Mu[j] + Mu[j + pstride];
            accl += fmaxf(vl, 0.f) * l_in[j] + fminf(vl, 0.f) * u_in[j];
            accu += fmaxf(vu, 0.f) * u_in[j] + fminf(vu, 0.f) * l_in[j];
        }
    } else if (same){
        for (int j = threadIdx.x; j < ncols; j += 256){
            float v = Ml[j];
            float p = fmaxf(v, 0.f), n = fminf(v, 0.f);
            accl += p * l_in[j] + n * u_in[j];
            accu += p * u_in[j] + n * l_in[j];
        }
    } else {
        for (int j = threadIdx.x; j < ncols; j += 256){
            float vl = Ml[j], vu = Mu[j];
            accl += fmaxf(vl, 0.f) * l_in[j] + fminf(vl, 0.f) * u_in[j];
            accu += fmaxf(vu, 0.f) * u_in[j] + fminf(vu, 0.f) * l_in[j];
        }
    }
    float tl, tu;
    block_reduce2_256(accl, accu, red, tl, tu);
    if (threadIdx.x == 0){
        float l = tl + c_l[row];
        float u = tu + c_u[row];
        float k1 = dspu_f(l), k2 = dspu_f(u);
        float klo = fminf(k1, k2), khi = fmaxf(k1, k2);
        float cwl = fminf(fmaxf(pl[row], klo), khi);
        float cwu = fminf(fmaxf(pu[row], klo), khi);
        float pts[4];
        pts[0] = l; pts[1] = u; pts[2] = 0.5f*(l+u); pts[3] = fminf(fmaxf(0.f, l), u);
        float bmin = INFINITY, bmax = -INFINITY;
        #pragma unroll
        for (int t = 0; t < 4; t++){
            float sp = spu_f(pts[t]);
            bmin = fminf(bmin, sp - cwl * pts[t]);
            bmax = fmaxf(bmax, sp - cwu * pts[t]);
        }
        wl[row] = cwl; wu[row] = cwu; bl[row] = bmin; bu[row] = bmax;
    }
}

// ---------- dapply: stage-start dual (S shared by l and u) ----------
__global__ __launch_bounds__(256) void dapply_dual(
    const float* __restrict__ S, const float* __restrict__ c_in,
    const float* __restrict__ wl, const float* __restrict__ wu,
    const float* __restrict__ bl, const float* __restrict__ bu,
    const float* __restrict__ bias_next,
    ushort_t* __restrict__ Ml, ushort_t* __restrict__ Mu,
    float* __restrict__ cl_out, float* __restrict__ cu_out, int ncols)
{
    __shared__ float red[8];
    int row = blockIdx.x;
    const float* Sr = S + (size_t)row * ncols;
    ushort_t* Mlr = Ml + (size_t)row * ncols;
    ushort_t* Mur = Mu + (size_t)row * ncols;
    float accl = 0.f, accu = 0.f;
    for (int j = threadIdx.x; j < ncols; j += 256){
        float v = Sr[j];
        float p = fmaxf(v, 0.f), n = fminf(v, 0.f);
        float wlj = wl[j], wuj = wu[j], blj = bl[j], buj = bu[j], bn = bias_next[j];
        float ml = p * wlj + n * wuj;
        float mu = p * wuj + n * wlj;
        Mlr[j] = f2bf(ml);
        Mur[j] = f2bf(mu);
        accl += p * blj + n * buj + ml * bn;
        accu += p * buj + n * blj + mu * bn;
    }
    float tl, tu;
    block_reduce2_256(accl, accu, red, tl, tu);
    if (threadIdx.x == 0){
        float c = c_in[row];
        cl_out[row] = c + tl;
        cu_out[row] = c + tu;
    }
}

// ---------- dapply: mid-stage pair (separate S_l,S_u), blockIdx.y = lu ----------
__global__ __launch_bounds__(256) void dapply_pair(
    const float* __restrict__ S_l, const float* __restrict__ S_u,
    const float* __restrict__ cl_in, const float* __restrict__ cu_in,
    const float* __restrict__ wl, const float* __restrict__ wu,
    const float* __restrict__ bl, const float* __restrict__ bu,
    const float* __restrict__ bias_next,
    ushort_t* __restrict__ Ml, ushort_t* __restrict__ Mu,
    float* __restrict__ cl_out, float* __restrict__ cu_out, int ncols)
{
    __shared__ float red[4];
    int row = blockIdx.x;
    int lu = blockIdx.y;
    const float* Sr = (lu ? S_u : S_l) + (size_t)row * ncols;
    const float* w_pos = lu ? wu : wl;
    const float* w_neg = lu ? wl : wu;
    const float* b_pos = lu ? bu : bl;
    const float* b_neg = lu ? bl : bu;
    ushort_t* Mr = (lu ? Mu : Ml) + (size_t)row * ncols;
    float acc = 0.f;
    for (int j = threadIdx.x; j < ncols; j += 256){
        float v = Sr[j];
        float p = fmaxf(v, 0.f), n = fminf(v, 0.f);
        float m = p * w_pos[j] + n * w_neg[j];
        Mr[j] = f2bf(m);
        acc += p * b_pos[j] + n * b_neg[j] + m * bias_next[j];
    }
    float t = block_reduce_256(acc, red);
    if (threadIdx.x == 0){
        if (lu) cu_out[row] = cu_in[row] + t;
        else    cl_out[row] = cl_in[row] + t;
    }
}

// final output: out[row] = c[row] + sum_j mix(M[row][j]; pos_b,neg_b)
__global__ __launch_bounds__(256) void input_reduce(
    const float* __restrict__ M, const float* __restrict__ c,
    const float* __restrict__ pos_b, const float* __restrict__ neg_b,
    float* __restrict__ out, int ncols, int ld)
{
    __shared__ float red[4];
    int row = blockIdx.x;
    const float* Mr = M + (size_t)row * ld;
    float acc = 0.f;
    for (int j = threadIdx.x; j < ncols; j += 256){
        float v = Mr[j];
        acc += fmaxf(v, 0.f) * pos_b[j] + fminf(v, 0.f) * neg_b[j];
    }
    float t = block_reduce_256(acc, red);
    if (threadIdx.x == 0) out[row] = t + c[row];
}

// combined weight conversion: z=0 -> W2, z=1 -> W1 (padded)
__global__ __launch_bounds__(256) void conv_both(
    const float* __restrict__ W2, ushort_t* __restrict__ T2,
    const float* __restrict__ W1, ushort_t* __restrict__ T1)
{
    __shared__ float tile[32][33];
    int z = blockIdx.z;
    const float* W = z ? W1 : W2;
    ushort_t* T = z ? T1 : T2;
    int K = H, N = z ? DIN : H, Npad = z ? DPAD : H;
    if (blockIdx.x * 32 >= Npad) return;   // uniform early-out for z=1 extra blocks
    int n0 = blockIdx.x * 32, k0 = blockIdx.y * 32;
    int tx = threadIdx.x & 31;
    int ty = threadIdx.x >> 5;   // 0..7
    #pragma unroll
    for (int i = 0; i < 32; i += 8){
        int k = k0 + ty + i, n = n0 + tx;
        tile[ty + i][tx] = (k < K && n < N) ? W[(size_t)k * N + n] : 0.f;
    }
    __syncthreads();
    #pragma unroll
    for (int i = 0; i < 32; i += 8){
        int n = n0 + ty + i, k = k0 + tx;
        if (n < Npad && k < K) T[(size_t)n * K + k] = f2bf(tile[tx][ty + i]);
    }
}

// ---------- MFMA GEMM pair: C_{l,u}[M][N] = A_{l,u}[M][K] @ BT[N][K]^T ----------
// blockIdx.z = lu*ksplit + ks; partial ks written to C + ks*part_stride (direct stores).
#define TM 128
#define TN 128
#define TK 32
__global__ __launch_bounds__(256) void gemm_mfma_pair(
    const ushort_t* __restrict__ A_l, const ushort_t* __restrict__ A_u,
    const ushort_t* __restrict__ BT,
    float* __restrict__ C_l, float* __restrict__ C_u,
    int M, int N, int K, int ksplit, size_t part_stride)
{
    __shared__ ushort_t As[TM * TK];   // [128][32] row-major
    __shared__ ushort_t Bs[TN * TK];
    int z = blockIdx.z;
    int lu = z / ksplit, ks = z - lu * ksplit;
    const ushort_t* A = lu ? A_u : A_l;
    float* C = (lu ? C_u : C_l) + (size_t)ks * part_stride;
    int Kpart = K / ksplit;
    int kbeg = ks * Kpart;

    int tid  = threadIdx.x;
    int wave = tid >> 6, lane = tid & 63;
    int wm = (wave >> 1) * 64, wn = (wave & 1) * 64;
    int l16 = lane & 15, quad = lane >> 4;
    int row0 = blockIdx.y * TM, col0 = blockIdx.x * TN;

    int r_lo = tid >> 2, kp = (tid & 3) * 8;
    const ushort_t* aSrc0 = A  + (size_t)(row0 + r_lo)      * K + kbeg + kp;
    const ushort_t* aSrc1 = A  + (size_t)(row0 + 64 + r_lo) * K + kbeg + kp;
    const ushort_t* bSrc0 = BT + (size_t)(col0 + r_lo)      * K + kbeg + kp;
    const ushort_t* bSrc1 = BT + (size_t)(col0 + 64 + r_lo) * K + kbeg + kp;
    ushort_t* aDst0 = As + wave * 512;
    ushort_t* aDst1 = As + 2048 + wave * 512;
    ushort_t* bDst0 = Bs + wave * 512;
    ushort_t* bDst1 = Bs + 2048 + wave * 512;

    f32x4 acc[4][4];
    #pragma unroll
    for (int i = 0; i < 4; i++)
        #pragma unroll
        for (int j = 0; j < 4; j++)
            acc[i][j] = (f32x4){0.f, 0.f, 0.f, 0.f};

    for (int kk0 = 0; kk0 < Kpart; kk0 += TK){
        load_lds16(aSrc0, aDst0);
        load_lds16(aSrc1, aDst1);
        load_lds16(bSrc0, bDst0);
        load_lds16(bSrc1, bDst1);
        aSrc0 += TK; aSrc1 += TK; bSrc0 += TK; bSrc1 += TK;
        __syncthreads();

        bf16x8 af[4], bfv[4];
        #pragma unroll
        for (int t = 0; t < 4; t++){
            af[t]  = *(const bf16x8*)&As[(wm + t*16 + l16) * TK + quad * 8];
            bfv[t] = *(const bf16x8*)&Bs[(wn + t*16 + l16) * TK + quad * 8];
        }
        #pragma unroll
        for (int i = 0; i < 4; i++)
            #pragma unroll
            for (int j = 0; j < 4; j++)
                acc[i][j] = __builtin_amdgcn_mfma_f32_16x16x32_bf16(af[i], bfv[j], acc[i][j], 0, 0, 0);
        __syncthreads();
    }

    // C/D layout: col = lane&15, row = quad*4 + reg
    #pragma unroll
    for (int i = 0; i < 4; i++){
        #pragma unroll
        for (int j = 0; j < 4; j++){
            int r0 = row0 + wm + i*16 + quad*4;
            int cc = col0 + wn + j*16 + l16;
            #pragma unroll
            for (int rr = 0; rr < 4; rr++)
                C[(size_t)(r0 + rr) * N + cc] = acc[i][j][rr];
        }
    }
}

// ---------- fused final-chain GEMV: D-transform + bias-dot + (9xK)@(KxN) ----------
// mode_w4: A source is W4 row-diffs (replaces final_init+dapply); else S (9xK fp32).
// C (9xN) and c_out (9) must be pre-zeroed; accumulated via atomicAdd.
#define GK9 128
__global__ __launch_bounds__(128) void gemv9_fused(
    const float* __restrict__ S,
    const float* __restrict__ W4, const float* __restrict__ b4,
    const int* __restrict__ tlp, int mode_w4,
    const float* __restrict__ c_in,
    const float* __restrict__ w_pos, const float* __restrict__ w_neg,
    const float* __restrict__ b_pos, const float* __restrict__ b_neg,
    const float* __restrict__ bias_next,
    const float* __restrict__ B, int K, int N,
    float* __restrict__ C, float* __restrict__ c_out)
{
    __shared__ float Alds[9][GK9];
    __shared__ float pr[9][2];
    int j = threadIdx.x;
    int k0 = blockIdx.y * GK9;
    int k = k0 + j;
    float wp = w_pos[k], wn = w_neg[k], bp = b_pos[k], bn = b_neg[k], bb = bias_next[k];
    int tl = mode_w4 ? *tlp : 0;
    float pc[9];
    #pragma unroll
    for (int r = 0; r < 9; r++){
        float v;
        if (mode_w4){
            int kr = r + (r >= tl ? 1 : 0);
            v = W4[(size_t)kr * K + k] - W4[(size_t)tl * K + k];
        } else {
            v = S[(size_t)r * K + k];
        }
        float p = fmaxf(v, 0.f), n = fminf(v, 0.f);
        float m = p * wp + n * wn;
        Alds[r][j] = m;
        pc[r] = p * bp + n * bn + m * bb;
    }
    if (blockIdx.x == 0){
        #pragma unroll
        for (int r = 0; r < 9; r++){
            float v = pc[r];
            #pragma unroll
            for (int off = 32; off > 0; off >>= 1) v += __shfl_down(v, off, 64);
            if ((j & 63) == 0) pr[r][j >> 6] = v;
        }
        __syncthreads();
        if (j < 9){
            float add = pr[j][0] + pr[j][1];
            if (blockIdx.y == 0)
                add += mode_w4 ? (b4[j + (j >= tl ? 1 : 0)] - b4[tl]) : c_in[j];
            atomicAdd(&c_out[j], add);
        }
    }
    __syncthreads();
    int col = blockIdx.x * GK9 + j;
    if (col < N){
        float acc[9] = {0.f,0.f,0.f,0.f,0.f,0.f,0.f,0.f,0.f};
        for (int kk = 0; kk < GK9; kk++){
            float b = B[(size_t)(k0 + kk) * N + col];
            #pragma unroll
            for (int r = 0; r < 9; r++) acc[r] += Alds[r][kk] * b;
        }
        #pragma unroll
        for (int r = 0; r < 9; r++) atomicAdd(&C[(size_t)r * N + col], acc[r]);
    }
}

extern "C" void kernel_launch(void* const* d_in, const int* in_sizes, int n_in,
                              void* d_out, int out_size, void* d_ws, size_t ws_size,
                              hipStream_t stream)
{
    const float* W1  = (const float*)d_in[0];
    const float* b1  = (const float*)d_in[1];
    const float* W2  = (const float*)d_in[2];
    const float* b2  = (const float*)d_in[3];
    const float* W3  = (const float*)d_in[4];
    const float* b3  = (const float*)d_in[5];
    const float* W4  = (const float*)d_in[6];
    const float* b4  = (const float*)d_in[7];
    const float* l_in = (const float*)d_in[8];
    const float* u_in = (const float*)d_in[9];
    const float* p_l1 = (const float*)d_in[10];
    const float* p_u1 = (const float*)d_in[11];
    const float* p_l2 = (const float*)d_in[12];
    const float* p_u2 = (const float*)d_in[13];
    const float* p_l3 = (const float*)d_in[14];
    const float* p_u3 = (const float*)d_in[15];
    const int*   tl   = (const int*)d_in[16];
    float* out = (float*)d_out;

    size_t off = 0;
    auto allocB = [&](size_t bytes) -> void* {
        void* p = (char*)d_ws + off;
        off += (bytes + 255) & ~(size_t)255;
        return p;
    };
    ushort_t* W1bt  = (ushort_t*)allocB((size_t)DPAD * H * 2);
    ushort_t* W2bt  = (ushort_t*)allocB((size_t)H * H * 2);
    ushort_t* Abf_l = (ushort_t*)allocB((size_t)H * H * 2);
    ushort_t* Abf_u = (ushort_t*)allocB((size_t)H * H * 2);
    float* B_l = (float*)allocB((size_t)H * H * 4);   // also holds 2 ND partials
    float* B_u = (float*)allocB((size_t)H * H * 4);
    float *wl1=(float*)allocB(H*4), *wu1=(float*)allocB(H*4), *bl1=(float*)allocB(H*4), *bu1=(float*)allocB(H*4);
    float *wl2=(float*)allocB(H*4), *wu2=(float*)allocB(H*4), *bl2=(float*)allocB(H*4), *bu2=(float*)allocB(H*4);
    float *wl3=(float*)allocB(H*4), *wu3=(float*)allocB(H*4), *bl3=(float*)allocB(H*4), *bu3=(float*)allocB(H*4);
    float *cl_a=(float*)allocB(H*4), *cl_b=(float*)allocB(H*4);
    float *cu_a=(float*)allocB(H*4), *cu_b=(float*)allocB(H*4);
    // final-chain buffers (contiguous; zeroed with ONE memset)
    size_t zero_begin = off;
    float* F1  = (float*)allocB(9 * H * 4);
    float* F2  = (float*)allocB(9 * H * 4);
    float* F3  = (float*)allocB(9 * DIN * 4);
    float *c9b=(float*)allocB(64), *c9c=(float*)allocB(64), *c9d=(float*)allocB(64);
    size_t zero_bytes = off - zero_begin;

    const size_t ND_PART = (size_t)H * DPAD;   // floats per ND partial

    dim3 blk(256);

    // 1. zero final-chain accumulators (single memset)
    hipMemsetAsync((char*)d_ws + zero_begin, 0, zero_bytes, stream);

    // 2. weight conversion (both in one dispatch)
    conv_both<<<dim3(H/32, H/32, 2), blk, 0, stream>>>(W2, W2bt, W1, W1bt);

    // 3. stage 1: bounds of layer-1 pre-activations (M_l == M_u == W1)
    bounds_fused<<<H, blk, 0, stream>>>(W1, W1, b1, b1, l_in, u_in, p_l1, p_u1,
                                        wl1, wu1, bl1, bu1, DIN, DIN, 0, 1);

    // 4-6. stage 2: (W2,b2) -> D1 -> @W1 -> bounds
    dapply_dual<<<H, blk, 0, stream>>>(W2, b2, wl1, wu1, bl1, bu1, b1,
                                       Abf_l, Abf_u, cl_a, cu_a, H);
    gemm_mfma_pair<<<dim3(DPAD/TN, H/TM, 4), blk, 0, stream>>>(
        Abf_l, Abf_u, W1bt, B_l, B_u, H, DPAD, H, 2, ND_PART);
    bounds_fused<<<H, blk, 0, stream>>>(B_l, B_u, cl_a, cu_a, l_in, u_in, p_l2, p_u2,
                                        wl2, wu2, bl2, bu2, DIN, DPAD, ND_PART, 0);

    // 7-11. stage 3: (W3,b3) -> D2 -> @W2 -> D1 -> @W1 -> bounds
    dapply_dual<<<H, blk, 0, stream>>>(W3, b3, wl2, wu2, bl2, bu2, b2,
                                       Abf_l, Abf_u, cl_a, cu_a, H);
    gemm_mfma_pair<<<dim3(H/TN, H/TM, 2), blk, 0, stream>>>(
        Abf_l, Abf_u, W2bt, B_l, B_u, H, H, H, 1, 0);
    dapply_pair<<<dim3(H, 2), blk, 0, stream>>>(B_l, B_u, cl_a, cu_a,
                                                wl1, wu1, bl1, bu1, b1,
                                                Abf_l, Abf_u, cl_b, cu_b, H);
    gemm_mfma_pair<<<dim3(DPAD/TN, H/TM, 4), blk, 0, stream>>>(
        Abf_l, Abf_u, W1bt, B_l, B_u, H, DPAD, H, 2, ND_PART);
    bounds_fused<<<H, blk, 0, stream>>>(B_l, B_u, cl_b, cu_b, l_in, u_in, p_l3, p_u3,
                                        wl3, wu3, bl3, bu3, DIN, DPAD, ND_PART, 0);

    // 12-15. final chain (upper bound only), 9 rows, fused transform+GEMV
    gemv9_fused<<<dim3(H/GK9, H/GK9), dim3(GK9), 0, stream>>>(
        nullptr, W4, b4, tl, 1, nullptr,
        wu3, wl3, bu3, bl3, b3, W3, H, H, F1, c9b);
    gemv9_fused<<<dim3(H/GK9, H/GK9), dim3(GK9), 0, stream>>>(
        F1, nullptr, nullptr, nullptr, 0, c9b,
        wu2, wl2, bu2, bl2, b2, W2, H, H, F2, c9c);
    gemv9_fused<<<dim3((DIN + GK9 - 1)/GK9, H/GK9), dim3(GK9), 0, stream>>>(
        F2, nullptr, nullptr, nullptr, 0, c9c,
        wu1, wl1, bu1, bl1, b1, W1, H, DIN, F3, c9d);
    input_reduce<<<9, blk, 0, stream>>>(F3, c9d, u_in, l_in, out, DIN, DIN);
}

// Round 5
// 387.880 us; speedup vs baseline: 8.6629x; 1.0668x over previous
//
#include <hip/hip_runtime.h>
#include <math.h>

#define H 2048
#define DIN 784
#define DPAD 896   // DIN padded to multiple of 128

typedef unsigned short ushort_t;
typedef __attribute__((ext_vector_type(8))) short bf16x8;
typedef __attribute__((ext_vector_type(4))) float f32x4;

// ---------- helpers ----------
__device__ __forceinline__ float spu_f(float x){
    if (x >= 0.0f) return x*x - 0.5f;
    float s = 1.0f / (1.0f + __expf(x));   // sigmoid(-x)
    return s - 1.0f;
}
__device__ __forceinline__ float dspu_f(float x){
    if (x >= 0.0f) return 2.0f*x;
    float s = 1.0f / (1.0f + __expf(x));
    return -s * (1.0f - s);
}
__device__ __forceinline__ ushort_t f2bf(float x){
    unsigned u = __float_as_uint(x);
    unsigned r = (u + 0x7FFFu + ((u >> 16) & 1u)) >> 16;
    return (ushort_t)r;
}
__device__ __forceinline__ float bf2f(ushort_t h){
    return __uint_as_float((unsigned)h << 16);
}
__device__ __forceinline__ void load_lds16(const void* g, void* l){
    __builtin_amdgcn_global_load_lds((const __attribute__((address_space(1))) void*)g,
                                     (__attribute__((address_space(3))) void*)l,
                                     16, 0, 0);
}
__device__ __forceinline__ float block_reduce_256(float v, float* red){
    #pragma unroll
    for (int off = 32; off > 0; off >>= 1) v += __shfl_down(v, off, 64);
    int lane = threadIdx.x & 63, w = threadIdx.x >> 6;
    if (lane == 0) red[w] = v;
    __syncthreads();
    float t = 0.f;
    if (threadIdx.x == 0) t = red[0] + red[1] + red[2] + red[3];
    return t;   // valid on thread 0 only
}
__device__ __forceinline__ void block_reduce2_256(float vl, float vu, float* red,
                                                  float& out_l, float& out_u){
    #pragma unroll
    for (int off = 32; off > 0; off >>= 1){
        vl += __shfl_down(vl, off, 64);
        vu += __shfl_down(vu, off, 64);
    }
    int lane = threadIdx.x & 63, w = threadIdx.x >> 6;
    if (lane == 0){ red[w] = vl; red[4 + w] = vu; }
    __syncthreads();
    if (threadIdx.x == 0){
        out_l = red[0] + red[1] + red[2] + red[3];
        out_u = red[4] + red[5] + red[6] + red[7];
    }
}
// shared SPU-relaxation epilogue (thread 0 only)
__device__ __forceinline__ void spu_relax(float l, float u, float pl, float pu,
                                          float& wl_o, float& wu_o, float& bl_o, float& bu_o){
    float k1 = dspu_f(l), k2 = dspu_f(u);
    float klo = fminf(k1, k2), khi = fmaxf(k1, k2);
    float cwl = fminf(fmaxf(pl, klo), khi);
    float cwu = fminf(fmaxf(pu, klo), khi);
    float pts[4];
    pts[0] = l; pts[1] = u; pts[2] = 0.5f*(l+u); pts[3] = fminf(fmaxf(0.f, l), u);
    float bmin = INFINITY, bmax = -INFINITY;
    #pragma unroll
    for (int t = 0; t < 4; t++){
        float sp = spu_f(pts[t]);
        bmin = fminf(bmin, sp - cwl * pts[t]);
        bmax = fmaxf(bmax, sp - cwu * pts[t]);
    }
    wl_o = cwl; wu_o = cwu; bl_o = bmin; bu_o = bmax;
}

// ---------- stage-1 bounds (M_l == M_u == W1, fp32) ----------
__global__ __launch_bounds__(256) void bounds_stage1(
    const float* __restrict__ W, const float* __restrict__ b,
    const float* __restrict__ l_in, const float* __restrict__ u_in,
    const float* __restrict__ pl, const float* __restrict__ pu,
    float* __restrict__ wl, float* __restrict__ wu,
    float* __restrict__ bl, float* __restrict__ bu, int ncols)
{
    __shared__ float red[8];
    int row = blockIdx.x;
    const float* Mr = W + (size_t)row * ncols;
    float accl = 0.f, accu = 0.f;
    for (int j = threadIdx.x; j < ncols; j += 256){
        float v = Mr[j];
        float p = fmaxf(v, 0.f), n = fminf(v, 0.f);
        accl += p * l_in[j] + n * u_in[j];
        accu += p * u_in[j] + n * l_in[j];
    }
    float tl, tu;
    block_reduce2_256(accl, accu, red, tl, tu);
    if (threadIdx.x == 0){
        float bb = b[row];
        spu_relax(tl + bb, tu + bb, pl[row], pu[row],
                  wl[row], wu[row], bl[row], bu[row]);
    }
}

// ---------- bounds from bf16 k-split partials ----------
__global__ __launch_bounds__(256) void bounds_parts(
    const ushort_t* __restrict__ P_l, const ushort_t* __restrict__ P_u,
    const float* __restrict__ c_l, const float* __restrict__ c_u,
    const float* __restrict__ l_in, const float* __restrict__ u_in,
    const float* __restrict__ pl, const float* __restrict__ pu,
    float* __restrict__ wl, float* __restrict__ wu,
    float* __restrict__ bl, float* __restrict__ bu,
    int ncols, int ld, size_t pstride, int nparts)
{
    __shared__ float red[8];
    int row = blockIdx.x;
    const ushort_t* Ml = P_l + (size_t)row * ld;
    const ushort_t* Mu = P_u + (size_t)row * ld;
    float accl = 0.f, accu = 0.f;
    for (int j = threadIdx.x; j < ncols; j += 256){
        float vl = 0.f, vu = 0.f;
        for (int s = 0; s < nparts; s++){
            vl += bf2f(Ml[j + (size_t)s * pstride]);
            vu += bf2f(Mu[j + (size_t)s * pstride]);
        }
        accl += fmaxf(vl, 0.f) * l_in[j] + fminf(vl, 0.f) * u_in[j];
        accu += fmaxf(vu, 0.f) * u_in[j] + fminf(vu, 0.f) * l_in[j];
    }
    float tl, tu;
    block_reduce2_256(accl, accu, red, tl, tu);
    if (threadIdx.x == 0){
        spu_relax(tl + c_l[row], tu + c_u[row], pl[row], pu[row],
                  wl[row], wu[row], bl[row], bu[row]);
    }
}

// ---------- dapply: stage-start dual (S shared by l and u, fp32) ----------
__global__ __launch_bounds__(256) void dapply_dual(
    const float* __restrict__ S, const float* __restrict__ c_in,
    const float* __restrict__ wl, const float* __restrict__ wu,
    const float* __restrict__ bl, const float* __restrict__ bu,
    const float* __restrict__ bias_next,
    ushort_t* __restrict__ Ml, ushort_t* __restrict__ Mu,
    float* __restrict__ cl_out, float* __restrict__ cu_out, int ncols)
{
    __shared__ float red[8];
    int row = blockIdx.x;
    const float* Sr = S + (size_t)row * ncols;
    ushort_t* Mlr = Ml + (size_t)row * ncols;
    ushort_t* Mur = Mu + (size_t)row * ncols;
    float accl = 0.f, accu = 0.f;
    for (int j = threadIdx.x; j < ncols; j += 256){
        float v = Sr[j];
        float p = fmaxf(v, 0.f), n = fminf(v, 0.f);
        float wlj = wl[j], wuj = wu[j], blj = bl[j], buj = bu[j], bn = bias_next[j];
        float ml = p * wlj + n * wuj;
        float mu = p * wuj + n * wlj;
        Mlr[j] = f2bf(ml);
        Mur[j] = f2bf(mu);
        accl += p * blj + n * buj + ml * bn;
        accu += p * buj + n * blj + mu * bn;
    }
    float tl, tu;
    block_reduce2_256(accl, accu, red, tl, tu);
    if (threadIdx.x == 0){
        float c = c_in[row];
        cl_out[row] = c + tl;
        cu_out[row] = c + tu;
    }
}

// ---------- dapply from bf16 k-split partials (blockIdx.y = lu) ----------
__global__ __launch_bounds__(256) void dapply_parts(
    const ushort_t* __restrict__ P_l, const ushort_t* __restrict__ P_u,
    const float* __restrict__ cl_in, const float* __restrict__ cu_in,
    const float* __restrict__ wl, const float* __restrict__ wu,
    const float* __restrict__ bl, const float* __restrict__ bu,
    const float* __restrict__ bias_next,
    ushort_t* __restrict__ Ml, ushort_t* __restrict__ Mu,
    float* __restrict__ cl_out, float* __restrict__ cu_out,
    int ncols, size_t pstride, int nparts)
{
    __shared__ float red[4];
    int row = blockIdx.x;
    int lu = blockIdx.y;
    const ushort_t* Sr = (lu ? P_u : P_l) + (size_t)row * ncols;
    const float* w_pos = lu ? wu : wl;
    const float* w_neg = lu ? wl : wu;
    const float* b_pos = lu ? bu : bl;
    const float* b_neg = lu ? bl : bu;
    ushort_t* Mr = (lu ? Mu : Ml) + (size_t)row * ncols;
    float acc = 0.f;
    for (int j = threadIdx.x; j < ncols; j += 256){
        float v = 0.f;
        for (int s = 0; s < nparts; s++) v += bf2f(Sr[j + (size_t)s * pstride]);
        float p = fmaxf(v, 0.f), n = fminf(v, 0.f);
        float m = p * w_pos[j] + n * w_neg[j];
        Mr[j] = f2bf(m);
        acc += p * b_pos[j] + n * b_neg[j] + m * bias_next[j];
    }
    float t = block_reduce_256(acc, red);
    if (threadIdx.x == 0){
        if (lu) cu_out[row] = cu_in[row] + t;
        else    cl_out[row] = cl_in[row] + t;
    }
}

// final output: out[row] = c[row] + sum_j mix(M[row][j]; pos_b,neg_b)
__global__ __launch_bounds__(256) void input_reduce(
    const float* __restrict__ M, const float* __restrict__ c,
    const float* __restrict__ pos_b, const float* __restrict__ neg_b,
    float* __restrict__ out, int ncols, int ld)
{
    __shared__ float red[4];
    int row = blockIdx.x;
    const float* Mr = M + (size_t)row * ld;
    float acc = 0.f;
    for (int j = threadIdx.x; j < ncols; j += 256){
        float v = Mr[j];
        acc += fmaxf(v, 0.f) * pos_b[j] + fminf(v, 0.f) * neg_b[j];
    }
    float t = block_reduce_256(acc, red);
    if (threadIdx.x == 0) out[row] = t + c[row];
}

// combined weight conversion: z=0 -> W2, z=1 -> W1 (padded)
__global__ __launch_bounds__(256) void conv_both(
    const float* __restrict__ W2, ushort_t* __restrict__ T2,
    const float* __restrict__ W1, ushort_t* __restrict__ T1)
{
    __shared__ float tile[32][33];
    int z = blockIdx.z;
    const float* W = z ? W1 : W2;
    ushort_t* T = z ? T1 : T2;
    int K = H, N = z ? DIN : H, Npad = z ? DPAD : H;
    if (blockIdx.x * 32 >= Npad) return;
    int n0 = blockIdx.x * 32, k0 = blockIdx.y * 32;
    int tx = threadIdx.x & 31;
    int ty = threadIdx.x >> 5;   // 0..7
    #pragma unroll
    for (int i = 0; i < 32; i += 8){
        int k = k0 + ty + i, n = n0 + tx;
        tile[ty + i][tx] = (k < K && n < N) ? W[(size_t)k * N + n] : 0.f;
    }
    __syncthreads();
    #pragma unroll
    for (int i = 0; i < 32; i += 8){
        int n = n0 + ty + i, k = k0 + tx;
        if (n < Npad && k < K) T[(size_t)n * K + k] = f2bf(tile[tx][ty + i]);
    }
}

// ---------- MFMA GEMM pair, bf16 partial output ----------
// C_{l,u} partial[ks][M][N] (bf16) = A_{l,u}[M][K(ks slice)] @ BT[N][K]^T
// blockIdx.z = lu*ksplit + ks; partial ks stored at C + ks*part_stride (ushort elems).
#define TM 128
#define TN 128
#define TK 32
__global__ __launch_bounds__(256) void gemm_mfma_pair(
    const ushort_t* __restrict__ A_l, const ushort_t* __restrict__ A_u,
    const ushort_t* __restrict__ BT,
    ushort_t* __restrict__ C_l, ushort_t* __restrict__ C_u,
    int M, int N, int K, int ksplit, size_t part_stride)
{
    __shared__ ushort_t As[TM * TK];   // [128][32] row-major
    __shared__ ushort_t Bs[TN * TK];
    int z = blockIdx.z;
    int lu = z / ksplit, ks = z - lu * ksplit;
    const ushort_t* A = lu ? A_u : A_l;
    ushort_t* C = (lu ? C_u : C_l) + (size_t)ks * part_stride;
    int Kpart = K / ksplit;
    int kbeg = ks * Kpart;

    int tid  = threadIdx.x;
    int wave = tid >> 6, lane = tid & 63;
    int wm = (wave >> 1) * 64, wn = (wave & 1) * 64;
    int l16 = lane & 15, quad = lane >> 4;
    int row0 = blockIdx.y * TM, col0 = blockIdx.x * TN;

    int r_lo = tid >> 2, kp = (tid & 3) * 8;
    const ushort_t* aSrc0 = A  + (size_t)(row0 + r_lo)      * K + kbeg + kp;
    const ushort_t* aSrc1 = A  + (size_t)(row0 + 64 + r_lo) * K + kbeg + kp;
    const ushort_t* bSrc0 = BT + (size_t)(col0 + r_lo)      * K + kbeg + kp;
    const ushort_t* bSrc1 = BT + (size_t)(col0 + 64 + r_lo) * K + kbeg + kp;
    ushort_t* aDst0 = As + wave * 512;
    ushort_t* aDst1 = As + 2048 + wave * 512;
    ushort_t* bDst0 = Bs + wave * 512;
    ushort_t* bDst1 = Bs + 2048 + wave * 512;

    f32x4 acc[4][4];
    #pragma unroll
    for (int i = 0; i < 4; i++)
        #pragma unroll
        for (int j = 0; j < 4; j++)
            acc[i][j] = (f32x4){0.f, 0.f, 0.f, 0.f};

    for (int kk0 = 0; kk0 < Kpart; kk0 += TK){
        load_lds16(aSrc0, aDst0);
        load_lds16(aSrc1, aDst1);
        load_lds16(bSrc0, bDst0);
        load_lds16(bSrc1, bDst1);
        aSrc0 += TK; aSrc1 += TK; bSrc0 += TK; bSrc1 += TK;
        __syncthreads();

        bf16x8 af[4], bfv[4];
        #pragma unroll
        for (int t = 0; t < 4; t++){
            af[t]  = *(const bf16x8*)&As[(wm + t*16 + l16) * TK + quad * 8];
            bfv[t] = *(const bf16x8*)&Bs[(wn + t*16 + l16) * TK + quad * 8];
        }
        #pragma unroll
        for (int i = 0; i < 4; i++)
            #pragma unroll
            for (int j = 0; j < 4; j++)
                acc[i][j] = __builtin_amdgcn_mfma_f32_16x16x32_bf16(af[i], bfv[j], acc[i][j], 0, 0, 0);
        __syncthreads();
    }

    // C/D layout: col = lane&15, row = quad*4 + reg
    #pragma unroll
    for (int i = 0; i < 4; i++){
        #pragma unroll
        for (int j = 0; j < 4; j++){
            int r0 = row0 + wm + i*16 + quad*4;
            int cc = col0 + wn + j*16 + l16;
            #pragma unroll
            for (int rr = 0; rr < 4; rr++)
                C[(size_t)(r0 + rr) * N + cc] = f2bf(acc[i][j][rr]);
        }
    }
}

// ---------- fused final-chain GEMV (9 rows), 64-thread blocks, GK9=64 ----------
// mode_w4: A source is W4 row-diffs; else S (9xK fp32).
// C (9xN) and c_out (9) must be pre-zeroed; accumulated via atomicAdd.
#define GK9 64
__global__ __launch_bounds__(64) void gemv9_fused(
    const float* __restrict__ S,
    const float* __restrict__ W4, const float* __restrict__ b4,
    const int* __restrict__ tlp, int mode_w4,
    const float* __restrict__ c_in,
    const float* __restrict__ w_pos, const float* __restrict__ w_neg,
    const float* __restrict__ b_pos, const float* __restrict__ b_neg,
    const float* __restrict__ bias_next,
    const float* __restrict__ B, int K, int N,
    float* __restrict__ C, float* __restrict__ c_out)
{
    __shared__ float Alds[9][GK9];
    int j = threadIdx.x;          // 0..63
    int k0 = blockIdx.y * GK9;
    int k = k0 + j;
    float wp = w_pos[k], wn = w_neg[k], bp = b_pos[k], bn = b_neg[k], bb = bias_next[k];
    int tl = mode_w4 ? *tlp : 0;
    float pc[9];
    #pragma unroll
    for (int r = 0; r < 9; r++){
        float v;
        if (mode_w4){
            int kr = r + (r >= tl ? 1 : 0);
            v = W4[(size_t)kr * K + k] - W4[(size_t)tl * K + k];
        } else {
            v = S[(size_t)r * K + k];
        }
        float p = fmaxf(v, 0.f), n = fminf(v, 0.f);
        float m = p * wp + n * wn;
        Alds[r][j] = m;
        pc[r] = p * bp + n * bn + m * bb;
    }
    if (blockIdx.x == 0){
        #pragma unroll
        for (int r = 0; r < 9; r++){
            float v = pc[r];
            #pragma unroll
            for (int o = 32; o > 0; o >>= 1) v += __shfl_down(v, o, 64);
            if (j == 0){
                if (blockIdx.y == 0)
                    v += mode_w4 ? (b4[r + (r >= tl ? 1 : 0)] - b4[tl]) : c_in[r];
                atomicAdd(&c_out[r], v);
            }
        }
    }
    __syncthreads();
    int col = blockIdx.x * GK9 + j;
    if (col < N){
        float acc[9] = {0.f,0.f,0.f,0.f,0.f,0.f,0.f,0.f,0.f};
        for (int kk = 0; kk < GK9; kk++){
            float b = B[(size_t)(k0 + kk) * N + col];
            #pragma unroll
            for (int r = 0; r < 9; r++) acc[r] += Alds[r][kk] * b;
        }
        #pragma unroll
        for (int r = 0; r < 9; r++) atomicAdd(&C[(size_t)r * N + col], acc[r]);
    }
}

extern "C" void kernel_launch(void* const* d_in, const int* in_sizes, int n_in,
                              void* d_out, int out_size, void* d_ws, size_t ws_size,
                              hipStream_t stream)
{
    const float* W1  = (const float*)d_in[0];
    const float* b1  = (const float*)d_in[1];
    const float* W2  = (const float*)d_in[2];
    const float* b2  = (const float*)d_in[3];
    const float* W3  = (const float*)d_in[4];
    const float* b3  = (const float*)d_in[5];
    const float* W4  = (const float*)d_in[6];
    const float* b4  = (const float*)d_in[7];
    const float* l_in = (const float*)d_in[8];
    const float* u_in = (const float*)d_in[9];
    const float* p_l1 = (const float*)d_in[10];
    const float* p_u1 = (const float*)d_in[11];
    const float* p_l2 = (const float*)d_in[12];
    const float* p_u2 = (const float*)d_in[13];
    const float* p_l3 = (const float*)d_in[14];
    const float* p_u3 = (const float*)d_in[15];
    const int*   tl   = (const int*)d_in[16];
    float* out = (float*)d_out;

    size_t off = 0;
    auto allocB = [&](size_t bytes) -> void* {
        void* p = (char*)d_ws + off;
        off += (bytes + 255) & ~(size_t)255;
        return p;
    };
    ushort_t* W1bt  = (ushort_t*)allocB((size_t)DPAD * H * 2);
    ushort_t* W2bt  = (ushort_t*)allocB((size_t)H * H * 2);
    ushort_t* Abf_l = (ushort_t*)allocB((size_t)H * H * 2);
    ushort_t* Abf_u = (ushort_t*)allocB((size_t)H * H * 2);
    // partial buffers: max(2 * H*H, 4 * H*DPAD) ushorts = 2*H*H ushorts
    ushort_t* P_l = (ushort_t*)allocB((size_t)2 * H * H * 2);
    ushort_t* P_u = (ushort_t*)allocB((size_t)2 * H * H * 2);
    float *wl1=(float*)allocB(H*4), *wu1=(float*)allocB(H*4), *bl1=(float*)allocB(H*4), *bu1=(float*)allocB(H*4);
    float *wl2=(float*)allocB(H*4), *wu2=(float*)allocB(H*4), *bl2=(float*)allocB(H*4), *bu2=(float*)allocB(H*4);
    float *wl3=(float*)allocB(H*4), *wu3=(float*)allocB(H*4), *bl3=(float*)allocB(H*4), *bu3=(float*)allocB(H*4);
    float *cl_a=(float*)allocB(H*4), *cl_b=(float*)allocB(H*4);
    float *cu_a=(float*)allocB(H*4), *cu_b=(float*)allocB(H*4);
    // final-chain buffers (contiguous; zeroed with ONE memset)
    size_t zero_begin = off;
    float* F1  = (float*)allocB(9 * H * 4);
    float* F2  = (float*)allocB(9 * H * 4);
    float* F3  = (float*)allocB(9 * DIN * 4);
    float *c9b=(float*)allocB(64), *c9c=(float*)allocB(64), *c9d=(float*)allocB(64);
    size_t zero_bytes = off - zero_begin;

    const size_t ND_PART = (size_t)H * DPAD;   // ushorts per ND partial
    const size_t NN_PART = (size_t)H * H;      // ushorts per NN partial

    dim3 blk(256);

    // 1. zero final-chain accumulators (single memset)
    hipMemsetAsync((char*)d_ws + zero_begin, 0, zero_bytes, stream);

    // 2. weight conversion (both in one dispatch)
    conv_both<<<dim3(H/32, H/32, 2), blk, 0, stream>>>(W2, W2bt, W1, W1bt);

    // 3. stage 1: bounds of layer-1 pre-activations
    bounds_stage1<<<H, blk, 0, stream>>>(W1, b1, l_in, u_in, p_l1, p_u1,
                                         wl1, wu1, bl1, bu1, DIN);

    // 4-6. stage 2: (W2,b2) -> D1 -> @W1 (ksplit=4) -> bounds
    dapply_dual<<<H, blk, 0, stream>>>(W2, b2, wl1, wu1, bl1, bu1, b1,
                                       Abf_l, Abf_u, cl_a, cu_a, H);
    gemm_mfma_pair<<<dim3(DPAD/TN, H/TM, 8), blk, 0, stream>>>(
        Abf_l, Abf_u, W1bt, P_l, P_u, H, DPAD, H, 4, ND_PART);
    bounds_parts<<<H, blk, 0, stream>>>(P_l, P_u, cl_a, cu_a, l_in, u_in, p_l2, p_u2,
                                        wl2, wu2, bl2, bu2, DIN, DPAD, ND_PART, 4);

    // 7-11. stage 3: (W3,b3) -> D2 -> @W2 (ksplit=2) -> D1 -> @W1 (ksplit=4) -> bounds
    dapply_dual<<<H, blk, 0, stream>>>(W3, b3, wl2, wu2, bl2, bu2, b2,
                                       Abf_l, Abf_u, cl_a, cu_a, H);
    gemm_mfma_pair<<<dim3(H/TN, H/TM, 4), blk, 0, stream>>>(
        Abf_l, Abf_u, W2bt, P_l, P_u, H, H, H, 2, NN_PART);
    dapply_parts<<<dim3(H, 2), blk, 0, stream>>>(P_l, P_u, cl_a, cu_a,
                                                 wl1, wu1, bl1, bu1, b1,
                                                 Abf_l, Abf_u, cl_b, cu_b, H, NN_PART, 2);
    gemm_mfma_pair<<<dim3(DPAD/TN, H/TM, 8), blk, 0, stream>>>(
        Abf_l, Abf_u, W1bt, P_l, P_u, H, DPAD, H, 4, ND_PART);
    bounds_parts<<<H, blk, 0, stream>>>(P_l, P_u, cl_b, cu_b, l_in, u_in, p_l3, p_u3,
                                        wl3, wu3, bl3, bu3, DIN, DPAD, ND_PART, 4);

    // 12-15. final chain (upper bound only), 9 rows, fused transform+GEMV
    gemv9_fused<<<dim3(H/GK9, H/GK9), dim3(GK9), 0, stream>>>(
        nullptr, W4, b4, tl, 1, nullptr,
        wu3, wl3, bu3, bl3, b3, W3, H, H, F1, c9b);
    gemv9_fused<<<dim3(H/GK9, H/GK9), dim3(GK9), 0, stream>>>(
        F1, nullptr, nullptr, nullptr, 0, c9b,
        wu2, wl2, bu2, bl2, b2, W2, H, H, F2, c9c);
    gemv9_fused<<<dim3((DIN + GK9 - 1)/GK9, H/GK9), dim3(GK9), 0, stream>>>(
        F2, nullptr, nullptr, nullptr, 0, c9c,
        wu1, wl1, bu1, bl1, b1, W1, H, DIN, F3, c9d);
    input_reduce<<<9, blk, 0, stream>>>(F3, c9d, u_in, l_in, out, DIN, DIN);
}

// Round 6
// 351.019 us; speedup vs baseline: 9.5726x; 1.1050x over previous
//
#include <hip/hip_runtime.h>
#include <math.h>

#define H 2048
#define DIN 784
#define DPAD 896   // DIN padded to multiple of 128

typedef unsigned short ushort_t;
typedef __attribute__((ext_vector_type(8))) short bf16x8;
typedef __attribute__((ext_vector_type(4))) float f32x4;
typedef __attribute__((ext_vector_type(4))) unsigned short u16x4;
union F4 { float4 v; float a[4]; };
union U4 { u16x4 v; ushort_t a[4]; };

// ---------- helpers ----------
__device__ __forceinline__ float spu_f(float x){
    if (x >= 0.0f) return x*x - 0.5f;
    float s = 1.0f / (1.0f + __expf(x));   // sigmoid(-x)
    return s - 1.0f;
}
__device__ __forceinline__ float dspu_f(float x){
    if (x >= 0.0f) return 2.0f*x;
    float s = 1.0f / (1.0f + __expf(x));
    return -s * (1.0f - s);
}
__device__ __forceinline__ ushort_t f2bf(float x){
    unsigned u = __float_as_uint(x);
    unsigned r = (u + 0x7FFFu + ((u >> 16) & 1u)) >> 16;
    return (ushort_t)r;
}
__device__ __forceinline__ float bf2f(ushort_t h){
    return __uint_as_float((unsigned)h << 16);
}
__device__ __forceinline__ void load_lds16(const void* g, void* l){
    __builtin_amdgcn_global_load_lds((const __attribute__((address_space(1))) void*)g,
                                     (__attribute__((address_space(3))) void*)l,
                                     16, 0, 0);
}
__device__ __forceinline__ float block_reduce_256(float v, float* red){
    #pragma unroll
    for (int off = 32; off > 0; off >>= 1) v += __shfl_down(v, off, 64);
    int lane = threadIdx.x & 63, w = threadIdx.x >> 6;
    if (lane == 0) red[w] = v;
    __syncthreads();
    float t = 0.f;
    if (threadIdx.x == 0) t = red[0] + red[1] + red[2] + red[3];
    return t;   // valid on thread 0 only
}
__device__ __forceinline__ void block_reduce2_256(float vl, float vu, float* red,
                                                  float& out_l, float& out_u){
    #pragma unroll
    for (int off = 32; off > 0; off >>= 1){
        vl += __shfl_down(vl, off, 64);
        vu += __shfl_down(vu, off, 64);
    }
    int lane = threadIdx.x & 63, w = threadIdx.x >> 6;
    if (lane == 0){ red[w] = vl; red[4 + w] = vu; }
    __syncthreads();
    if (threadIdx.x == 0){
        out_l = red[0] + red[1] + red[2] + red[3];
        out_u = red[4] + red[5] + red[6] + red[7];
    }
}
__device__ __forceinline__ void spu_relax(float l, float u, float pl, float pu,
                                          float& wl_o, float& wu_o, float& bl_o, float& bu_o){
    float k1 = dspu_f(l), k2 = dspu_f(u);
    float klo = fminf(k1, k2), khi = fmaxf(k1, k2);
    float cwl = fminf(fmaxf(pl, klo), khi);
    float cwu = fminf(fmaxf(pu, klo), khi);
    float pts[4];
    pts[0] = l; pts[1] = u; pts[2] = 0.5f*(l+u); pts[3] = fminf(fmaxf(0.f, l), u);
    float bmin = INFINITY, bmax = -INFINITY;
    #pragma unroll
    for (int t = 0; t < 4; t++){
        float sp = spu_f(pts[t]);
        bmin = fminf(bmin, sp - cwl * pts[t]);
        bmax = fmaxf(bmax, sp - cwu * pts[t]);
    }
    wl_o = cwl; wu_o = cwu; bl_o = bmin; bu_o = bmax;
}

// ---------- merged: weight conversion (z=0,1) + stage-1 bounds (z=2) ----------
__global__ __launch_bounds__(256) void conv_bounds1(
    const float* __restrict__ W2, ushort_t* __restrict__ T2,
    const float* __restrict__ W1, ushort_t* __restrict__ T1,
    const float* __restrict__ b1,
    const float* __restrict__ l_in, const float* __restrict__ u_in,
    const float* __restrict__ pl, const float* __restrict__ pu,
    float* __restrict__ wl, float* __restrict__ wu,
    float* __restrict__ bl, float* __restrict__ bu)
{
    int z = blockIdx.z;
    if (z < 2){
        __shared__ float tile[32][33];
        const float* W = z ? W1 : W2;
        ushort_t* T = z ? T1 : T2;
        int K = H, N = z ? DIN : H, Npad = z ? DPAD : H;
        if (blockIdx.x * 32 >= (unsigned)Npad) return;
        int n0 = blockIdx.x * 32, k0 = blockIdx.y * 32;
        int tx = threadIdx.x & 31;
        int ty = threadIdx.x >> 5;   // 0..7
        #pragma unroll
        for (int i = 0; i < 32; i += 8){
            int k = k0 + ty + i, n = n0 + tx;
            tile[ty + i][tx] = (k < K && n < N) ? W[(size_t)k * N + n] : 0.f;
        }
        __syncthreads();
        #pragma unroll
        for (int i = 0; i < 32; i += 8){
            int n = n0 + ty + i, k = k0 + tx;
            if (n < Npad && k < K) T[(size_t)n * K + k] = f2bf(tile[tx][ty + i]);
        }
        return;
    }
    // z == 2: stage-1 bounds, row = blockIdx.y*64 + blockIdx.x
    int row = blockIdx.y * 64 + blockIdx.x;
    if (row >= H) return;
    __shared__ float red[8];
    const F4* Mr = (const F4*)(W1 + (size_t)row * DIN);
    const F4* li4 = (const F4*)l_in;
    const F4* ui4 = (const F4*)u_in;
    float accl = 0.f, accu = 0.f;
    for (int q = threadIdx.x; q < DIN/4; q += 256){
        F4 v = Mr[q], lo = li4[q], up = ui4[q];
        #pragma unroll
        for (int c = 0; c < 4; c++){
            float p = fmaxf(v.a[c], 0.f), n = fminf(v.a[c], 0.f);
            accl += p * lo.a[c] + n * up.a[c];
            accu += p * up.a[c] + n * lo.a[c];
        }
    }
    float tl, tu;
    block_reduce2_256(accl, accu, red, tl, tu);
    if (threadIdx.x == 0){
        float bb = b1[row];
        spu_relax(tl + bb, tu + bb, pl[row], pu[row],
                  wl[row], wu[row], bl[row], bu[row]);
    }
}

// ---------- bounds from bf16 k-split partials (vectorized x4) ----------
__global__ __launch_bounds__(256) void bounds_parts(
    const ushort_t* __restrict__ P_l, const ushort_t* __restrict__ P_u,
    const float* __restrict__ c_l, const float* __restrict__ c_u,
    const float* __restrict__ l_in, const float* __restrict__ u_in,
    const float* __restrict__ pl, const float* __restrict__ pu,
    float* __restrict__ wl, float* __restrict__ wu,
    float* __restrict__ bl, float* __restrict__ bu,
    int ncols, int ld, size_t pstride, int nparts)
{
    __shared__ float red[8];
    int row = blockIdx.x;
    const ushort_t* Ml = P_l + (size_t)row * ld;
    const ushort_t* Mu = P_u + (size_t)row * ld;
    const F4* li4 = (const F4*)l_in;
    const F4* ui4 = (const F4*)u_in;
    float accl = 0.f, accu = 0.f;
    for (int q = threadIdx.x; q < ncols/4; q += 256){
        float vl[4] = {0.f,0.f,0.f,0.f}, vu[4] = {0.f,0.f,0.f,0.f};
        for (int s = 0; s < nparts; s++){
            U4 a, b;
            a.v = *(const u16x4*)&Ml[(size_t)s * pstride + q*4];
            b.v = *(const u16x4*)&Mu[(size_t)s * pstride + q*4];
            #pragma unroll
            for (int c = 0; c < 4; c++){ vl[c] += bf2f(a.a[c]); vu[c] += bf2f(b.a[c]); }
        }
        F4 lo = li4[q], up = ui4[q];
        #pragma unroll
        for (int c = 0; c < 4; c++){
            accl += fmaxf(vl[c], 0.f) * lo.a[c] + fminf(vl[c], 0.f) * up.a[c];
            accu += fmaxf(vu[c], 0.f) * up.a[c] + fminf(vu[c], 0.f) * lo.a[c];
        }
    }
    float tl, tu;
    block_reduce2_256(accl, accu, red, tl, tu);
    if (threadIdx.x == 0){
        spu_relax(tl + c_l[row], tu + c_u[row], pl[row], pu[row],
                  wl[row], wu[row], bl[row], bu[row]);
    }
}

// ---------- dapply: stage-start dual (S shared by l and u, fp32, vectorized) ----------
__global__ __launch_bounds__(256) void dapply_dual(
    const float* __restrict__ S, const float* __restrict__ c_in,
    const float* __restrict__ wl, const float* __restrict__ wu,
    const float* __restrict__ bl, const float* __restrict__ bu,
    const float* __restrict__ bias_next,
    ushort_t* __restrict__ Ml, ushort_t* __restrict__ Mu,
    float* __restrict__ cl_out, float* __restrict__ cu_out, int ncols)
{
    __shared__ float red[8];
    int row = blockIdx.x;
    const F4* S4 = (const F4*)(S + (size_t)row * ncols);
    u16x4* Ml4 = (u16x4*)(Ml + (size_t)row * ncols);
    u16x4* Mu4 = (u16x4*)(Mu + (size_t)row * ncols);
    const F4* wl4 = (const F4*)wl; const F4* wu4 = (const F4*)wu;
    const F4* bl4 = (const F4*)bl; const F4* bu4 = (const F4*)bu;
    const F4* bn4 = (const F4*)bias_next;
    float accl = 0.f, accu = 0.f;
    for (int q = threadIdx.x; q < ncols/4; q += 256){
        F4 v = S4[q], a = wl4[q], b = wu4[q], c = bl4[q], d = bu4[q], e = bn4[q];
        U4 rl, ru;
        #pragma unroll
        for (int k = 0; k < 4; k++){
            float p = fmaxf(v.a[k], 0.f), n = fminf(v.a[k], 0.f);
            float ml = p * a.a[k] + n * b.a[k];
            float mu = p * b.a[k] + n * a.a[k];
            rl.a[k] = f2bf(ml);
            ru.a[k] = f2bf(mu);
            accl += p * c.a[k] + n * d.a[k] + ml * e.a[k];
            accu += p * d.a[k] + n * c.a[k] + mu * e.a[k];
        }
        Ml4[q] = rl.v;
        Mu4[q] = ru.v;
    }
    float tl, tu;
    block_reduce2_256(accl, accu, red, tl, tu);
    if (threadIdx.x == 0){
        float cc = c_in[row];
        cl_out[row] = cc + tl;
        cu_out[row] = cc + tu;
    }
}

// ---------- dapply from bf16 k-split partials (blockIdx.y = lu, vectorized) ----------
__global__ __launch_bounds__(256) void dapply_parts(
    const ushort_t* __restrict__ P_l, const ushort_t* __restrict__ P_u,
    const float* __restrict__ cl_in, const float* __restrict__ cu_in,
    const float* __restrict__ wl, const float* __restrict__ wu,
    const float* __restrict__ bl, const float* __restrict__ bu,
    const float* __restrict__ bias_next,
    ushort_t* __restrict__ Ml, ushort_t* __restrict__ Mu,
    float* __restrict__ cl_out, float* __restrict__ cu_out,
    int ncols, size_t pstride, int nparts)
{
    __shared__ float red[4];
    int row = blockIdx.x;
    int lu = blockIdx.y;
    const ushort_t* Sr = (lu ? P_u : P_l) + (size_t)row * ncols;
    const F4* wp4 = (const F4*)(lu ? wu : wl);
    const F4* wn4 = (const F4*)(lu ? wl : wu);
    const F4* bp4 = (const F4*)(lu ? bu : bl);
    const F4* bn4_ = (const F4*)(lu ? bl : bu);
    const F4* bb4 = (const F4*)bias_next;
    u16x4* Mr4 = (u16x4*)((lu ? Mu : Ml) + (size_t)row * ncols);
    float acc = 0.f;
    for (int q = threadIdx.x; q < ncols/4; q += 256){
        float vv[4] = {0.f,0.f,0.f,0.f};
        for (int s = 0; s < nparts; s++){
            U4 t; t.v = *(const u16x4*)&Sr[(size_t)s * pstride + q*4];
            #pragma unroll
            for (int c = 0; c < 4; c++) vv[c] += bf2f(t.a[c]);
        }
        F4 a = wp4[q], b = wn4[q], c4 = bp4[q], d = bn4_[q], e = bb4[q];
        U4 r;
        #pragma unroll
        for (int c = 0; c < 4; c++){
            float p = fmaxf(vv[c], 0.f), n = fminf(vv[c], 0.f);
            float m = p * a.a[c] + n * b.a[c];
            r.a[c] = f2bf(m);
            acc += p * c4.a[c] + n * d.a[c] + m * e.a[c];
        }
        Mr4[q] = r.v;
    }
    float t = block_reduce_256(acc, red);
    if (threadIdx.x == 0){
        if (lu) cu_out[row] = cu_in[row] + t;
        else    cl_out[row] = cl_in[row] + t;
    }
}

// final output: out[row] = c[row] + sum_j mix(M[row][j]; pos_b,neg_b)
__global__ __launch_bounds__(256) void input_reduce(
    const float* __restrict__ M, const float* __restrict__ c,
    const float* __restrict__ pos_b, const float* __restrict__ neg_b,
    float* __restrict__ out, int ncols, int ld)
{
    __shared__ float red[4];
    int row = blockIdx.x;
    const float* Mr = M + (size_t)row * ld;
    float acc = 0.f;
    for (int j = threadIdx.x; j < ncols; j += 256){
        float v = Mr[j];
        acc += fmaxf(v, 0.f) * pos_b[j] + fminf(v, 0.f) * neg_b[j];
    }
    float t = block_reduce_256(acc, red);
    if (threadIdx.x == 0) out[row] = t + c[row];
}

// ---------- MFMA GEMM pair, TK=64, XOR-swizzled LDS, bf16 partial output ----------
// blockIdx.z = lu*ksplit + ks; partial ks stored at C + ks*part_stride (ushort elems).
// LDS layout: tile[row][chunk], chunk slot s holds global k-chunk c = s ^ (row & 7)
// (8-byte-element chunks of 8 bf16). Keeps ds_read at 2-way bank aliasing (free).
#define TM 128
#define TN 128
#define TK 64
__global__ __launch_bounds__(256) void gemm_mfma_pair(
    const ushort_t* __restrict__ A_l, const ushort_t* __restrict__ A_u,
    const ushort_t* __restrict__ BT,
    ushort_t* __restrict__ C_l, ushort_t* __restrict__ C_u,
    int M, int N, int K, int ksplit, size_t part_stride)
{
    __shared__ ushort_t As[TM * TK];   // [128][64]
    __shared__ ushort_t Bs[TN * TK];
    int z = blockIdx.z;
    int lu = z / ksplit, ks = z - lu * ksplit;
    const ushort_t* A = lu ? A_u : A_l;
    ushort_t* C = (lu ? C_u : C_l) + (size_t)ks * part_stride;
    int Kpart = K / ksplit;
    int kbeg = ks * Kpart;

    int tid  = threadIdx.x;
    int wave = tid >> 6, lane = tid & 63;
    int wm = (wave >> 1) * 64, wn = (wave & 1) * 64;
    int l16 = lane & 15, quad = lane >> 4;
    int row0 = blockIdx.y * TM, col0 = blockIdx.x * TN;

    // staging: per call, 32 rows; row r_lo = tid>>3, chunk slot tid&7 gets
    // global chunk (tid&7) ^ (r_lo&7)  (XOR swizzle)
    int r_lo = tid >> 3;                       // 0..31
    int kp = (((tid & 7) ^ (r_lo & 7)) * 8);   // swizzled source k-offset
    const ushort_t *aSrc[4], *bSrc[4];
    ushort_t *aDst[4], *bDst[4];
    #pragma unroll
    for (int g = 0; g < 4; g++){
        aSrc[g] = A  + (size_t)(row0 + g*32 + r_lo) * K + kbeg + kp;
        bSrc[g] = BT + (size_t)(col0 + g*32 + r_lo) * K + kbeg + kp;
        aDst[g] = As + g*2048 + wave*512;
        bDst[g] = Bs + g*2048 + wave*512;
    }

    f32x4 acc[4][4];
    #pragma unroll
    for (int i = 0; i < 4; i++)
        #pragma unroll
        for (int j = 0; j < 4; j++)
            acc[i][j] = (f32x4){0.f, 0.f, 0.f, 0.f};

    for (int kk0 = 0; kk0 < Kpart; kk0 += TK){
        #pragma unroll
        for (int g = 0; g < 4; g++) load_lds16(aSrc[g], aDst[g]);
        #pragma unroll
        for (int g = 0; g < 4; g++) load_lds16(bSrc[g], bDst[g]);
        #pragma unroll
        for (int g = 0; g < 4; g++){ aSrc[g] += TK; bSrc[g] += TK; }
        __syncthreads();

        #pragma unroll
        for (int half = 0; half < 2; half++){
            bf16x8 af[4], bfv[4];
            #pragma unroll
            for (int t = 0; t < 4; t++){
                int ra = wm + t*16 + l16;
                int rb = wn + t*16 + l16;
                int ca = (half*4 + quad) ^ (ra & 7);   // swizzled chunk slot
                int cb = (half*4 + quad) ^ (rb & 7);
                af[t]  = *(const bf16x8*)&As[ra * TK + ca * 8];
                bfv[t] = *(const bf16x8*)&Bs[rb * TK + cb * 8];
            }
            #pragma unroll
            for (int i = 0; i < 4; i++)
                #pragma unroll
                for (int j = 0; j < 4; j++)
                    acc[i][j] = __builtin_amdgcn_mfma_f32_16x16x32_bf16(af[i], bfv[j], acc[i][j], 0, 0, 0);
        }
        __syncthreads();
    }

    // C/D layout: col = lane&15, row = quad*4 + reg
    #pragma unroll
    for (int i = 0; i < 4; i++){
        #pragma unroll
        for (int j = 0; j < 4; j++){
            int r0 = row0 + wm + i*16 + quad*4;
            int cc = col0 + wn + j*16 + l16;
            #pragma unroll
            for (int rr = 0; rr < 4; rr++)
                C[(size_t)(r0 + rr) * N + cc] = f2bf(acc[i][j][rr]);
        }
    }
}

// ---------- fused final-chain GEMV (9 rows), 64-thread blocks, GK9=64 ----------
#define GK9 64
__global__ __launch_bounds__(64) void gemv9_fused(
    const float* __restrict__ S,
    const float* __restrict__ W4, const float* __restrict__ b4,
    const int* __restrict__ tlp, int mode_w4,
    const float* __restrict__ c_in,
    const float* __restrict__ w_pos, const float* __restrict__ w_neg,
    const float* __restrict__ b_pos, const float* __restrict__ b_neg,
    const float* __restrict__ bias_next,
    const float* __restrict__ B, int K, int N,
    float* __restrict__ C, float* __restrict__ c_out)
{
    __shared__ float Alds[9][GK9];
    int j = threadIdx.x;          // 0..63
    int k0 = blockIdx.y * GK9;
    int k = k0 + j;
    float wp = w_pos[k], wn = w_neg[k], bp = b_pos[k], bn = b_neg[k], bb = bias_next[k];
    int tl = mode_w4 ? *tlp : 0;
    float pc[9];
    #pragma unroll
    for (int r = 0; r < 9; r++){
        float v;
        if (mode_w4){
            int kr = r + (r >= tl ? 1 : 0);
            v = W4[(size_t)kr * K + k] - W4[(size_t)tl * K + k];
        } else {
            v = S[(size_t)r * K + k];
        }
        float p = fmaxf(v, 0.f), n = fminf(v, 0.f);
        float m = p * wp + n * wn;
        Alds[r][j] = m;
        pc[r] = p * bp + n * bn + m * bb;
    }
    if (blockIdx.x == 0){
        #pragma unroll
        for (int r = 0; r < 9; r++){
            float v = pc[r];
            #pragma unroll
            for (int o = 32; o > 0; o >>= 1) v += __shfl_down(v, o, 64);
            if (j == 0){
                if (blockIdx.y == 0)
                    v += mode_w4 ? (b4[r + (r >= tl ? 1 : 0)] - b4[tl]) : c_in[r];
                atomicAdd(&c_out[r], v);
            }
        }
    }
    __syncthreads();
    int col = blockIdx.x * GK9 + j;
    if (col < N){
        float acc[9] = {0.f,0.f,0.f,0.f,0.f,0.f,0.f,0.f,0.f};
        for (int kk = 0; kk < GK9; kk++){
            float b = B[(size_t)(k0 + kk) * N + col];
            #pragma unroll
            for (int r = 0; r < 9; r++) acc[r] += Alds[r][kk] * b;
        }
        #pragma unroll
        for (int r = 0; r < 9; r++) atomicAdd(&C[(size_t)r * N + col], acc[r]);
    }
}

extern "C" void kernel_launch(void* const* d_in, const int* in_sizes, int n_in,
                              void* d_out, int out_size, void* d_ws, size_t ws_size,
                              hipStream_t stream)
{
    const float* W1  = (const float*)d_in[0];
    const float* b1  = (const float*)d_in[1];
    const float* W2  = (const float*)d_in[2];
    const float* b2  = (const float*)d_in[3];
    const float* W3  = (const float*)d_in[4];
    const float* b3  = (const float*)d_in[5];
    const float* W4  = (const float*)d_in[6];
    const float* b4  = (const float*)d_in[7];
    const float* l_in = (const float*)d_in[8];
    const float* u_in = (const float*)d_in[9];
    const float* p_l1 = (const float*)d_in[10];
    const float* p_u1 = (const float*)d_in[11];
    const float* p_l2 = (const float*)d_in[12];
    const float* p_u2 = (const float*)d_in[13];
    const float* p_l3 = (const float*)d_in[14];
    const float* p_u3 = (const float*)d_in[15];
    const int*   tl   = (const int*)d_in[16];
    float* out = (float*)d_out;

    size_t off = 0;
    auto allocB = [&](size_t bytes) -> void* {
        void* p = (char*)d_ws + off;
        off += (bytes + 255) & ~(size_t)255;
        return p;
    };
    ushort_t* W1bt  = (ushort_t*)allocB((size_t)DPAD * H * 2);
    ushort_t* W2bt  = (ushort_t*)allocB((size_t)H * H * 2);
    ushort_t* Abf_l = (ushort_t*)allocB((size_t)H * H * 2);
    ushort_t* Abf_u = (ushort_t*)allocB((size_t)H * H * 2);
    ushort_t* P_l = (ushort_t*)allocB((size_t)2 * H * H * 2);
    ushort_t* P_u = (ushort_t*)allocB((size_t)2 * H * H * 2);
    float *wl1=(float*)allocB(H*4), *wu1=(float*)allocB(H*4), *bl1=(float*)allocB(H*4), *bu1=(float*)allocB(H*4);
    float *wl2=(float*)allocB(H*4), *wu2=(float*)allocB(H*4), *bl2=(float*)allocB(H*4), *bu2=(float*)allocB(H*4);
    float *wl3=(float*)allocB(H*4), *wu3=(float*)allocB(H*4), *bl3=(float*)allocB(H*4), *bu3=(float*)allocB(H*4);
    float *cl_a=(float*)allocB(H*4), *cl_b=(float*)allocB(H*4);
    float *cu_a=(float*)allocB(H*4), *cu_b=(float*)allocB(H*4);
    size_t zero_begin = off;
    float* F1  = (float*)allocB(9 * H * 4);
    float* F2  = (float*)allocB(9 * H * 4);
    float* F3  = (float*)allocB(9 * DIN * 4);
    float *c9b=(float*)allocB(64), *c9c=(float*)allocB(64), *c9d=(float*)allocB(64);
    size_t zero_bytes = off - zero_begin;

    const size_t ND_PART = (size_t)H * DPAD;   // ushorts per ND partial
    const size_t NN_PART = (size_t)H * H;      // ushorts per NN partial

    dim3 blk(256);

    // 1. zero final-chain accumulators
    hipMemsetAsync((char*)d_ws + zero_begin, 0, zero_bytes, stream);

    // 2. weight conversion + stage-1 bounds (merged)
    conv_bounds1<<<dim3(H/32, H/32, 3), blk, 0, stream>>>(
        W2, W2bt, W1, W1bt, b1, l_in, u_in, p_l1, p_u1, wl1, wu1, bl1, bu1);

    // 3-5. stage 2: (W2,b2) -> D1 -> @W1 (ksplit=4) -> bounds
    dapply_dual<<<H, blk, 0, stream>>>(W2, b2, wl1, wu1, bl1, bu1, b1,
                                       Abf_l, Abf_u, cl_a, cu_a, H);
    gemm_mfma_pair<<<dim3(DPAD/TN, H/TM, 8), blk, 0, stream>>>(
        Abf_l, Abf_u, W1bt, P_l, P_u, H, DPAD, H, 4, ND_PART);
    bounds_parts<<<H, blk, 0, stream>>>(P_l, P_u, cl_a, cu_a, l_in, u_in, p_l2, p_u2,
                                        wl2, wu2, bl2, bu2, DIN, DPAD, ND_PART, 4);

    // 6-10. stage 3: (W3,b3) -> D2 -> @W2 (ksplit=2) -> D1 -> @W1 (ksplit=4) -> bounds
    dapply_dual<<<H, blk, 0, stream>>>(W3, b3, wl2, wu2, bl2, bu2, b2,
                                       Abf_l, Abf_u, cl_a, cu_a, H);
    gemm_mfma_pair<<<dim3(H/TN, H/TM, 4), blk, 0, stream>>>(
        Abf_l, Abf_u, W2bt, P_l, P_u, H, H, H, 2, NN_PART);
    dapply_parts<<<dim3(H, 2), blk, 0, stream>>>(P_l, P_u, cl_a, cu_a,
                                                 wl1, wu1, bl1, bu1, b1,
                                                 Abf_l, Abf_u, cl_b, cu_b, H, NN_PART, 2);
    gemm_mfma_pair<<<dim3(DPAD/TN, H/TM, 8), blk, 0, stream>>>(
        Abf_l, Abf_u, W1bt, P_l, P_u, H, DPAD, H, 4, ND_PART);
    bounds_parts<<<H, blk, 0, stream>>>(P_l, P_u, cl_b, cu_b, l_in, u_in, p_l3, p_u3,
                                        wl3, wu3, bl3, bu3, DIN, DPAD, ND_PART, 4);

    // 11-14. final chain (upper bound only), 9 rows
    gemv9_fused<<<dim3(H/GK9, H/GK9), dim3(GK9), 0, stream>>>(
        nullptr, W4, b4, tl, 1, nullptr,
        wu3, wl3, bu3, bl3, b3, W3, H, H, F1, c9b);
    gemv9_fused<<<dim3(H/GK9, H/GK9), dim3(GK9), 0, stream>>>(
        F1, nullptr, nullptr, nullptr, 0, c9b,
        wu2, wl2, bu2, bl2, b2, W2, H, H, F2, c9c);
    gemv9_fused<<<dim3((DIN + GK9 - 1)/GK9, H/GK9), dim3(GK9), 0, stream>>>(
        F2, nullptr, nullptr, nullptr, 0, c9c,
        wu1, wl1, bu1, bl1, b1, W1, H, DIN, F3, c9d);
    input_reduce<<<9, blk, 0, stream>>>(F3, c9d, u_in, l_in, out, DIN, DIN);
}

// Round 7
// 329.014 us; speedup vs baseline: 10.2128x; 1.0669x over previous
//
#include <hip/hip_runtime.h>
#include <math.h>

#define H 2048
#define DIN 784
#define DPAD 896   // DIN padded to multiple of 128

typedef unsigned short ushort_t;
typedef __attribute__((ext_vector_type(8))) short bf16x8;
typedef __attribute__((ext_vector_type(4))) float f32x4;
typedef __attribute__((ext_vector_type(4))) unsigned short u16x4;
typedef __attribute__((ext_vector_type(8))) unsigned short u16x8;
union F4 { float4 v; float a[4]; };
union U4 { u16x4 v; ushort_t a[4]; };
union U8 { u16x8 v; ushort_t a[8]; };

// ---------- helpers ----------
__device__ __forceinline__ float spu_f(float x){
    if (x >= 0.0f) return x*x - 0.5f;
    float s = 1.0f / (1.0f + __expf(x));   // sigmoid(-x)
    return s - 1.0f;
}
__device__ __forceinline__ float dspu_f(float x){
    if (x >= 0.0f) return 2.0f*x;
    float s = 1.0f / (1.0f + __expf(x));
    return -s * (1.0f - s);
}
__device__ __forceinline__ ushort_t f2bf(float x){
    unsigned u = __float_as_uint(x);
    unsigned r = (u + 0x7FFFu + ((u >> 16) & 1u)) >> 16;
    return (ushort_t)r;
}
__device__ __forceinline__ float bf2f(ushort_t h){
    return __uint_as_float((unsigned)h << 16);
}
__device__ __forceinline__ void load_lds16(const void* g, void* l){
    __builtin_amdgcn_global_load_lds((const __attribute__((address_space(1))) void*)g,
                                     (__attribute__((address_space(3))) void*)l,
                                     16, 0, 0);
}
__device__ __forceinline__ float block_reduce_256(float v, float* red){
    #pragma unroll
    for (int off = 32; off > 0; off >>= 1) v += __shfl_down(v, off, 64);
    int lane = threadIdx.x & 63, w = threadIdx.x >> 6;
    if (lane == 0) red[w] = v;
    __syncthreads();
    float t = 0.f;
    if (threadIdx.x == 0) t = red[0] + red[1] + red[2] + red[3];
    return t;   // valid on thread 0 only
}
__device__ __forceinline__ void block_reduce2_256(float vl, float vu, float* red,
                                                  float& out_l, float& out_u){
    #pragma unroll
    for (int off = 32; off > 0; off >>= 1){
        vl += __shfl_down(vl, off, 64);
        vu += __shfl_down(vu, off, 64);
    }
    int lane = threadIdx.x & 63, w = threadIdx.x >> 6;
    if (lane == 0){ red[w] = vl; red[4 + w] = vu; }
    __syncthreads();
    if (threadIdx.x == 0){
        out_l = red[0] + red[1] + red[2] + red[3];
        out_u = red[4] + red[5] + red[6] + red[7];
    }
}
__device__ __forceinline__ void spu_relax(float l, float u, float pl, float pu,
                                          float& wl_o, float& wu_o, float& bl_o, float& bu_o){
    float k1 = dspu_f(l), k2 = dspu_f(u);
    float klo = fminf(k1, k2), khi = fmaxf(k1, k2);
    float cwl = fminf(fmaxf(pl, klo), khi);
    float cwu = fminf(fmaxf(pu, klo), khi);
    float pts[4];
    pts[0] = l; pts[1] = u; pts[2] = 0.5f*(l+u); pts[3] = fminf(fmaxf(0.f, l), u);
    float bmin = INFINITY, bmax = -INFINITY;
    #pragma unroll
    for (int t = 0; t < 4; t++){
        float sp = spu_f(pts[t]);
        bmin = fminf(bmin, sp - cwl * pts[t]);
        bmax = fmaxf(bmax, sp - cwu * pts[t]);
    }
    wl_o = cwl; wu_o = cwu; bl_o = bmin; bu_o = bmax;
}

// ---------- merged: weight conversion (z=0,1) + stage-1 bounds (z=2) ----------
__global__ __launch_bounds__(256) void conv_bounds1(
    const float* __restrict__ W2, ushort_t* __restrict__ T2,
    const float* __restrict__ W1, ushort_t* __restrict__ T1,
    const float* __restrict__ b1,
    const float* __restrict__ l_in, const float* __restrict__ u_in,
    const float* __restrict__ pl, const float* __restrict__ pu,
    float* __restrict__ wl, float* __restrict__ wu,
    float* __restrict__ bl, float* __restrict__ bu)
{
    int z = blockIdx.z;
    if (z < 2){
        __shared__ float tile[32][33];
        const float* W = z ? W1 : W2;
        ushort_t* T = z ? T1 : T2;
        int K = H, N = z ? DIN : H, Npad = z ? DPAD : H;
        if (blockIdx.x * 32 >= (unsigned)Npad) return;
        int n0 = blockIdx.x * 32, k0 = blockIdx.y * 32;
        int tx = threadIdx.x & 31;
        int ty = threadIdx.x >> 5;   // 0..7
        #pragma unroll
        for (int i = 0; i < 32; i += 8){
            int k = k0 + ty + i, n = n0 + tx;
            tile[ty + i][tx] = (k < K && n < N) ? W[(size_t)k * N + n] : 0.f;
        }
        __syncthreads();
        #pragma unroll
        for (int i = 0; i < 32; i += 8){
            int n = n0 + ty + i, k = k0 + tx;
            if (n < Npad && k < K) T[(size_t)n * K + k] = f2bf(tile[tx][ty + i]);
        }
        return;
    }
    // z == 2: stage-1 bounds, row = blockIdx.y*64 + blockIdx.x
    int row = blockIdx.y * 64 + blockIdx.x;
    if (row >= H) return;
    __shared__ float red[8];
    const F4* Mr = (const F4*)(W1 + (size_t)row * DIN);
    const F4* li4 = (const F4*)l_in;
    const F4* ui4 = (const F4*)u_in;
    float accl = 0.f, accu = 0.f;
    for (int q = threadIdx.x; q < DIN/4; q += 256){
        F4 v = Mr[q], lo = li4[q], up = ui4[q];
        #pragma unroll
        for (int c = 0; c < 4; c++){
            float p = fmaxf(v.a[c], 0.f), n = fminf(v.a[c], 0.f);
            accl += p * lo.a[c] + n * up.a[c];
            accu += p * up.a[c] + n * lo.a[c];
        }
    }
    float tl, tu;
    block_reduce2_256(accl, accu, red, tl, tu);
    if (threadIdx.x == 0){
        float bb = b1[row];
        spu_relax(tl + bb, tu + bb, pl[row], pu[row],
                  wl[row], wu[row], bl[row], bu[row]);
    }
}

// ---------- bounds from bf16 k-split partials (vectorized x4) ----------
__global__ __launch_bounds__(256) void bounds_parts(
    const ushort_t* __restrict__ P_l, const ushort_t* __restrict__ P_u,
    const float* __restrict__ c_l, const float* __restrict__ c_u,
    const float* __restrict__ l_in, const float* __restrict__ u_in,
    const float* __restrict__ pl, const float* __restrict__ pu,
    float* __restrict__ wl, float* __restrict__ wu,
    float* __restrict__ bl, float* __restrict__ bu,
    int ncols, int ld, size_t pstride, int nparts)
{
    __shared__ float red[8];
    int row = blockIdx.x;
    const ushort_t* Ml = P_l + (size_t)row * ld;
    const ushort_t* Mu = P_u + (size_t)row * ld;
    const F4* li4 = (const F4*)l_in;
    const F4* ui4 = (const F4*)u_in;
    float accl = 0.f, accu = 0.f;
    for (int q = threadIdx.x; q < ncols/4; q += 256){
        float vl[4] = {0.f,0.f,0.f,0.f}, vu[4] = {0.f,0.f,0.f,0.f};
        for (int s = 0; s < nparts; s++){
            U4 a, b;
            a.v = *(const u16x4*)&Ml[(size_t)s * pstride + q*4];
            b.v = *(const u16x4*)&Mu[(size_t)s * pstride + q*4];
            #pragma unroll
            for (int c = 0; c < 4; c++){ vl[c] += bf2f(a.a[c]); vu[c] += bf2f(b.a[c]); }
        }
        F4 lo = li4[q], up = ui4[q];
        #pragma unroll
        for (int c = 0; c < 4; c++){
            accl += fmaxf(vl[c], 0.f) * lo.a[c] + fminf(vl[c], 0.f) * up.a[c];
            accu += fmaxf(vu[c], 0.f) * up.a[c] + fminf(vu[c], 0.f) * lo.a[c];
        }
    }
    float tl, tu;
    block_reduce2_256(accl, accu, red, tl, tu);
    if (threadIdx.x == 0){
        spu_relax(tl + c_l[row], tu + c_u[row], pl[row], pu[row],
                  wl[row], wu[row], bl[row], bu[row]);
    }
}

// ---------- dapply: stage-start dual (S shared by l and u, fp32, vectorized) ----------
__global__ __launch_bounds__(256) void dapply_dual(
    const float* __restrict__ S, const float* __restrict__ c_in,
    const float* __restrict__ wl, const float* __restrict__ wu,
    const float* __restrict__ bl, const float* __restrict__ bu,
    const float* __restrict__ bias_next,
    ushort_t* __restrict__ Ml, ushort_t* __restrict__ Mu,
    float* __restrict__ cl_out, float* __restrict__ cu_out, int ncols)
{
    __shared__ float red[8];
    int row = blockIdx.x;
    const F4* S4 = (const F4*)(S + (size_t)row * ncols);
    u16x4* Ml4 = (u16x4*)(Ml + (size_t)row * ncols);
    u16x4* Mu4 = (u16x4*)(Mu + (size_t)row * ncols);
    const F4* wl4 = (const F4*)wl; const F4* wu4 = (const F4*)wu;
    const F4* bl4 = (const F4*)bl; const F4* bu4 = (const F4*)bu;
    const F4* bn4 = (const F4*)bias_next;
    float accl = 0.f, accu = 0.f;
    for (int q = threadIdx.x; q < ncols/4; q += 256){
        F4 v = S4[q], a = wl4[q], b = wu4[q], c = bl4[q], d = bu4[q], e = bn4[q];
        U4 rl, ru;
        #pragma unroll
        for (int k = 0; k < 4; k++){
            float p = fmaxf(v.a[k], 0.f), n = fminf(v.a[k], 0.f);
            float ml = p * a.a[k] + n * b.a[k];
            float mu = p * b.a[k] + n * a.a[k];
            rl.a[k] = f2bf(ml);
            ru.a[k] = f2bf(mu);
            accl += p * c.a[k] + n * d.a[k] + ml * e.a[k];
            accu += p * d.a[k] + n * c.a[k] + mu * e.a[k];
        }
        Ml4[q] = rl.v;
        Mu4[q] = ru.v;
    }
    float tl, tu;
    block_reduce2_256(accl, accu, red, tl, tu);
    if (threadIdx.x == 0){
        float cc = c_in[row];
        cl_out[row] = cc + tl;
        cu_out[row] = cc + tu;
    }
}

// ---------- dapply from bf16 partials (blockIdx.y = lu, 16B loads) ----------
__global__ __launch_bounds__(256) void dapply_parts(
    const ushort_t* __restrict__ P_l, const ushort_t* __restrict__ P_u,
    const float* __restrict__ cl_in, const float* __restrict__ cu_in,
    const float* __restrict__ wl, const float* __restrict__ wu,
    const float* __restrict__ bl, const float* __restrict__ bu,
    const float* __restrict__ bias_next,
    ushort_t* __restrict__ Ml, ushort_t* __restrict__ Mu,
    float* __restrict__ cl_out, float* __restrict__ cu_out,
    int ncols, size_t pstride, int nparts)
{
    __shared__ float red[4];
    int row = blockIdx.x;
    int lu = blockIdx.y;
    const ushort_t* Sr = (lu ? P_u : P_l) + (size_t)row * ncols;
    const float* w_pos = lu ? wu : wl;
    const float* w_neg = lu ? wl : wu;
    const float* b_pos = lu ? bu : bl;
    const float* b_neg = lu ? bl : bu;
    u16x8* Mr8 = (u16x8*)((lu ? Mu : Ml) + (size_t)row * ncols);
    float acc = 0.f;
    for (int q = threadIdx.x; q < ncols/8; q += 256){
        float vv[8];
        {
            U8 t; t.v = *(const u16x8*)&Sr[q*8];
            #pragma unroll
            for (int c = 0; c < 8; c++) vv[c] = bf2f(t.a[c]);
        }
        for (int s = 1; s < nparts; s++){
            U8 t; t.v = *(const u16x8*)&Sr[(size_t)s * pstride + q*8];
            #pragma unroll
            for (int c = 0; c < 8; c++) vv[c] += bf2f(t.a[c]);
        }
        U8 r;
        #pragma unroll
        for (int c = 0; c < 8; c++){
            int j = q*8 + c;
            float p = fmaxf(vv[c], 0.f), n = fminf(vv[c], 0.f);
            float m = p * w_pos[j] + n * w_neg[j];
            r.a[c] = f2bf(m);
            acc += p * b_pos[j] + n * b_neg[j] + m * bias_next[j];
        }
        Mr8[q] = r.v;
    }
    float t = block_reduce_256(acc, red);
    if (threadIdx.x == 0){
        if (lu) cu_out[row] = cu_in[row] + t;
        else    cl_out[row] = cl_in[row] + t;
    }
}

// final output: out[row] = c[row] + sum_j mix(M[row][j]; pos_b,neg_b)
__global__ __launch_bounds__(256) void input_reduce(
    const float* __restrict__ M, const float* __restrict__ c,
    const float* __restrict__ pos_b, const float* __restrict__ neg_b,
    float* __restrict__ out, int ncols, int ld)
{
    __shared__ float red[4];
    int row = blockIdx.x;
    const float* Mr = M + (size_t)row * ld;
    float acc = 0.f;
    for (int j = threadIdx.x; j < ncols; j += 256){
        float v = Mr[j];
        acc += fmaxf(v, 0.f) * pos_b[j] + fminf(v, 0.f) * neg_b[j];
    }
    float t = block_reduce_256(acc, red);
    if (threadIdx.x == 0) out[row] = t + c[row];
}

// ---------- MFMA GEMM pair, 128x64 block tile, 64x32 wave tile ----------
// TK=64, XOR-swizzled LDS, bf16 partial output. acc = 32 AGPRs/wave so that
// total regs <= 128 -> 4 waves/SIMD (m69 bucket) -> 4 blocks/CU.
#define TM 128
#define TN 64
#define TK 64
__global__ __launch_bounds__(256, 4) void gemm_mfma_pair(
    const ushort_t* __restrict__ A_l, const ushort_t* __restrict__ A_u,
    const ushort_t* __restrict__ BT,
    ushort_t* __restrict__ C_l, ushort_t* __restrict__ C_u,
    int M, int N, int K, int ksplit, size_t part_stride)
{
    __shared__ ushort_t As[TM * TK];   // [128][64] 16 KB
    __shared__ ushort_t Bs[TN * TK];   // [64][64]   8 KB
    int z = blockIdx.z;
    int lu = z / ksplit, ks = z - lu * ksplit;
    const ushort_t* A = lu ? A_u : A_l;
    ushort_t* C = (lu ? C_u : C_l) + (size_t)ks * part_stride;
    int Kpart = K / ksplit;
    int kbeg = ks * Kpart;

    int tid  = threadIdx.x;
    int wave = tid >> 6, lane = tid & 63;
    int wm = (wave >> 1) * 64, wn = (wave & 1) * 32;
    int l16 = lane & 15, quad = lane >> 4;
    int row0 = blockIdx.y * TM, col0 = blockIdx.x * TN;

    // staging: row r_lo = tid>>3 (0..31), chunk slot tid&7 holds global chunk
    // (tid&7) ^ (r_lo&7). A: 4 row-groups of 32; B: 2 row-groups of 32.
    int r_lo = tid >> 3;
    int kp = (((tid & 7) ^ (r_lo & 7)) * 8);
    const ushort_t *aSrc[4], *bSrc[2];
    ushort_t *aDst[4], *bDst[2];
    #pragma unroll
    for (int g = 0; g < 4; g++){
        aSrc[g] = A + (size_t)(row0 + g*32 + r_lo) * K + kbeg + kp;
        aDst[g] = As + g*2048 + wave*512;
    }
    #pragma unroll
    for (int g = 0; g < 2; g++){
        bSrc[g] = BT + (size_t)(col0 + g*32 + r_lo) * K + kbeg + kp;
        bDst[g] = Bs + g*2048 + wave*512;
    }

    f32x4 acc[4][2];
    #pragma unroll
    for (int i = 0; i < 4; i++)
        #pragma unroll
        for (int j = 0; j < 2; j++)
            acc[i][j] = (f32x4){0.f, 0.f, 0.f, 0.f};

    for (int kk0 = 0; kk0 < Kpart; kk0 += TK){
        #pragma unroll
        for (int g = 0; g < 4; g++) load_lds16(aSrc[g], aDst[g]);
        #pragma unroll
        for (int g = 0; g < 2; g++) load_lds16(bSrc[g], bDst[g]);
        #pragma unroll
        for (int g = 0; g < 4; g++) aSrc[g] += TK;
        #pragma unroll
        for (int g = 0; g < 2; g++) bSrc[g] += TK;
        __syncthreads();

        #pragma unroll
        for (int half = 0; half < 2; half++){
            bf16x8 af[4], bf[2];
            #pragma unroll
            for (int t = 0; t < 4; t++){
                int ra = wm + t*16 + l16;
                int sa = (half*4 + quad) ^ (ra & 7);
                af[t] = *(const bf16x8*)&As[ra * TK + sa * 8];
            }
            #pragma unroll
            for (int t = 0; t < 2; t++){
                int rb = wn + t*16 + l16;
                int sb = (half*4 + quad) ^ (rb & 7);
                bf[t] = *(const bf16x8*)&Bs[rb * TK + sb * 8];
            }
            #pragma unroll
            for (int i = 0; i < 4; i++)
                #pragma unroll
                for (int j = 0; j < 2; j++)
                    acc[i][j] = __builtin_amdgcn_mfma_f32_16x16x32_bf16(af[i], bf[j], acc[i][j], 0, 0, 0);
        }
        __syncthreads();
    }

    // C/D layout: col = lane&15, row = quad*4 + reg
    #pragma unroll
    for (int i = 0; i < 4; i++){
        #pragma unroll
        for (int j = 0; j < 2; j++){
            int r0 = row0 + wm + i*16 + quad*4;
            int cc = col0 + wn + j*16 + l16;
            #pragma unroll
            for (int rr = 0; rr < 4; rr++)
                C[(size_t)(r0 + rr) * N + cc] = f2bf(acc[i][j][rr]);
        }
    }
}

// ---------- fused final-chain GEMV (9 rows), 64-thread blocks, GK9=64 ----------
#define GK9 64
__global__ __launch_bounds__(64) void gemv9_fused(
    const float* __restrict__ S,
    const float* __restrict__ W4, const float* __restrict__ b4,
    const int* __restrict__ tlp, int mode_w4,
    const float* __restrict__ c_in,
    const float* __restrict__ w_pos, const float* __restrict__ w_neg,
    const float* __restrict__ b_pos, const float* __restrict__ b_neg,
    const float* __restrict__ bias_next,
    const float* __restrict__ B, int K, int N,
    float* __restrict__ C, float* __restrict__ c_out)
{
    __shared__ float Alds[9][GK9];
    int j = threadIdx.x;          // 0..63
    int k0 = blockIdx.y * GK9;
    int k = k0 + j;
    float wp = w_pos[k], wn = w_neg[k], bp = b_pos[k], bn = b_neg[k], bb = bias_next[k];
    int tl = mode_w4 ? *tlp : 0;
    float pc[9];
    #pragma unroll
    for (int r = 0; r < 9; r++){
        float v;
        if (mode_w4){
            int kr = r + (r >= tl ? 1 : 0);
            v = W4[(size_t)kr * K + k] - W4[(size_t)tl * K + k];
        } else {
            v = S[(size_t)r * K + k];
        }
        float p = fmaxf(v, 0.f), n = fminf(v, 0.f);
        float m = p * wp + n * wn;
        Alds[r][j] = m;
        pc[r] = p * bp + n * bn + m * bb;
    }
    if (blockIdx.x == 0){
        #pragma unroll
        for (int r = 0; r < 9; r++){
            float v = pc[r];
            #pragma unroll
            for (int o = 32; o > 0; o >>= 1) v += __shfl_down(v, o, 64);
            if (j == 0){
                if (blockIdx.y == 0)
                    v += mode_w4 ? (b4[r + (r >= tl ? 1 : 0)] - b4[tl]) : c_in[r];
                atomicAdd(&c_out[r], v);
            }
        }
    }
    __syncthreads();
    int col = blockIdx.x * GK9 + j;
    if (col < N){
        float acc[9] = {0.f,0.f,0.f,0.f,0.f,0.f,0.f,0.f,0.f};
        for (int kk = 0; kk < GK9; kk++){
            float b = B[(size_t)(k0 + kk) * N + col];
            #pragma unroll
            for (int r = 0; r < 9; r++) acc[r] += Alds[r][kk] * b;
        }
        #pragma unroll
        for (int r = 0; r < 9; r++) atomicAdd(&C[(size_t)r * N + col], acc[r]);
    }
}

extern "C" void kernel_launch(void* const* d_in, const int* in_sizes, int n_in,
                              void* d_out, int out_size, void* d_ws, size_t ws_size,
                              hipStream_t stream)
{
    const float* W1  = (const float*)d_in[0];
    const float* b1  = (const float*)d_in[1];
    const float* W2  = (const float*)d_in[2];
    const float* b2  = (const float*)d_in[3];
    const float* W3  = (const float*)d_in[4];
    const float* b3  = (const float*)d_in[5];
    const float* W4  = (const float*)d_in[6];
    const float* b4  = (const float*)d_in[7];
    const float* l_in = (const float*)d_in[8];
    const float* u_in = (const float*)d_in[9];
    const float* p_l1 = (const float*)d_in[10];
    const float* p_u1 = (const float*)d_in[11];
    const float* p_l2 = (const float*)d_in[12];
    const float* p_u2 = (const float*)d_in[13];
    const float* p_l3 = (const float*)d_in[14];
    const float* p_u3 = (const float*)d_in[15];
    const int*   tl   = (const int*)d_in[16];
    float* out = (float*)d_out;

    size_t off = 0;
    auto allocB = [&](size_t bytes) -> void* {
        void* p = (char*)d_ws + off;
        off += (bytes + 255) & ~(size_t)255;
        return p;
    };
    ushort_t* W1bt  = (ushort_t*)allocB((size_t)DPAD * H * 2);
    ushort_t* W2bt  = (ushort_t*)allocB((size_t)H * H * 2);
    ushort_t* Abf_l = (ushort_t*)allocB((size_t)H * H * 2);
    ushort_t* Abf_u = (ushort_t*)allocB((size_t)H * H * 2);
    ushort_t* P_l = (ushort_t*)allocB((size_t)2 * H * H * 2);
    ushort_t* P_u = (ushort_t*)allocB((size_t)2 * H * H * 2);
    float *wl1=(float*)allocB(H*4), *wu1=(float*)allocB(H*4), *bl1=(float*)allocB(H*4), *bu1=(float*)allocB(H*4);
    float *wl2=(float*)allocB(H*4), *wu2=(float*)allocB(H*4), *bl2=(float*)allocB(H*4), *bu2=(float*)allocB(H*4);
    float *wl3=(float*)allocB(H*4), *wu3=(float*)allocB(H*4), *bl3=(float*)allocB(H*4), *bu3=(float*)allocB(H*4);
    float *cl_a=(float*)allocB(H*4), *cl_b=(float*)allocB(H*4);
    float *cu_a=(float*)allocB(H*4), *cu_b=(float*)allocB(H*4);
    size_t zero_begin = off;
    float* F1  = (float*)allocB(9 * H * 4);
    float* F2  = (float*)allocB(9 * H * 4);
    float* F3  = (float*)allocB(9 * DIN * 4);
    float *c9b=(float*)allocB(64), *c9c=(float*)allocB(64), *c9d=(float*)allocB(64);
    size_t zero_bytes = off - zero_begin;

    const size_t ND_PART = (size_t)H * DPAD;   // ushorts per ND partial
    const size_t NN_PART = (size_t)H * H;      // ushorts per NN partial (unused, ksplit=1)

    dim3 blk(256);

    // 1. zero final-chain accumulators
    hipMemsetAsync((char*)d_ws + zero_begin, 0, zero_bytes, stream);

    // 2. weight conversion + stage-1 bounds (merged)
    conv_bounds1<<<dim3(H/32, H/32, 3), blk, 0, stream>>>(
        W2, W2bt, W1, W1bt, b1, l_in, u_in, p_l1, p_u1, wl1, wu1, bl1, bu1);

    // 3-5. stage 2: (W2,b2) -> D1 -> @W1 (ksplit=2) -> bounds
    dapply_dual<<<H, blk, 0, stream>>>(W2, b2, wl1, wu1, bl1, bu1, b1,
                                       Abf_l, Abf_u, cl_a, cu_a, H);
    gemm_mfma_pair<<<dim3(DPAD/TN, H/TM, 4), blk, 0, stream>>>(
        Abf_l, Abf_u, W1bt, P_l, P_u, H, DPAD, H, 2, ND_PART);
    bounds_parts<<<H, blk, 0, stream>>>(P_l, P_u, cl_a, cu_a, l_in, u_in, p_l2, p_u2,
                                        wl2, wu2, bl2, bu2, DIN, DPAD, ND_PART, 2);

    // 6-10. stage 3: (W3,b3) -> D2 -> @W2 (ksplit=1) -> D1 -> @W1 (ksplit=2) -> bounds
    dapply_dual<<<H, blk, 0, stream>>>(W3, b3, wl2, wu2, bl2, bu2, b2,
                                       Abf_l, Abf_u, cl_a, cu_a, H);
    gemm_mfma_pair<<<dim3(H/TN, H/TM, 2), blk, 0, stream>>>(
        Abf_l, Abf_u, W2bt, P_l, P_u, H, H, H, 1, NN_PART);
    dapply_parts<<<dim3(H, 2), blk, 0, stream>>>(P_l, P_u, cl_a, cu_a,
                                                 wl1, wu1, bl1, bu1, b1,
                                                 Abf_l, Abf_u, cl_b, cu_b, H, NN_PART, 1);
    gemm_mfma_pair<<<dim3(DPAD/TN, H/TM, 4), blk, 0, stream>>>(
        Abf_l, Abf_u, W1bt, P_l, P_u, H, DPAD, H, 2, ND_PART);
    bounds_parts<<<H, blk, 0, stream>>>(P_l, P_u, cl_b, cu_b, l_in, u_in, p_l3, p_u3,
                                        wl3, wu3, bl3, bu3, DIN, DPAD, ND_PART, 2);

    // 11-14. final chain (upper bound only), 9 rows
    gemv9_fused<<<dim3(H/GK9, H/GK9), dim3(GK9), 0, stream>>>(
        nullptr, W4, b4, tl, 1, nullptr,
        wu3, wl3, bu3, bl3, b3, W3, H, H, F1, c9b);
    gemv9_fused<<<dim3(H/GK9, H/GK9), dim3(GK9), 0, stream>>>(
        F1, nullptr, nullptr, nullptr, 0, c9b,
        wu2, wl2, bu2, bl2, b2, W2, H, H, F2, c9c);
    gemv9_fused<<<dim3((DIN + GK9 - 1)/GK9, H/GK9), dim3(GK9), 0, stream>>>(
        F2, nullptr, nullptr, nullptr, 0, c9c,
        wu1, wl1, bu1, bl1, b1, W1, H, DIN, F3, c9d);
    input_reduce<<<9, blk, 0, stream>>>(F3, c9d, u_in, l_in, out, DIN, DIN);
}